// Round 1
// baseline (740.588 us; speedup 1.0000x reference)
//
#include <hip/hip_runtime.h>
#include <hip/hip_bf16.h>

typedef __attribute__((ext_vector_type(8))) short s16x8;
typedef __attribute__((ext_vector_type(8))) unsigned short u16x8;
typedef __attribute__((ext_vector_type(4))) float f32x4;

__device__ __forceinline__ float bf2f(unsigned short u) {
  union { unsigned int i; float f; } v; v.i = ((unsigned int)u) << 16; return v.f;
}
__device__ __forceinline__ unsigned short f2bf(float f) {
  union { float f; unsigned int i; } v; v.f = f;
  unsigned int u = v.i;
  unsigned int r = (u + 0x7fffu + ((u >> 16) & 1u)) >> 16;
  return (unsigned short)r;
}
__device__ __forceinline__ float eluf(float x) { return x > 0.f ? x : expf(x) - 1.f; }
__device__ __forceinline__ float sigf(float x) { return 1.f / (1.f + expf(-x)); }

struct GP {
  const float* a0; const float* a1; const float* a2;   // f32 A sources
  const unsigned short* ab; long lda;                  // bf16 A source
  const float* b0; const float* b1; const float* b2; long ldb;
  const float* bias;       // PEB=0: per-n bias
  const float* peb;        // PEB=1: [m/512][N] bias (includes base bias)
  const float* bnS; const float* bnT;                  // EPI=3
  float* of; unsigned short* ob; unsigned short* ob2;
  int N, K;
};

// AM: 0 = f32 (a0, lda); 1 = bf16 (ab, lda); 2 = concat[x(512)|ph(1024)];
//     3 = concat[x(512)|ph(1024)|attn_f(1024)]
template<int AM>
__device__ __forceinline__ u16x8 load_a8(const GP& p, int row, int col) {
  if constexpr (AM == 1) {
    return *(const u16x8*)(p.ab + (size_t)row * p.lda + col);
  } else {
    const float* s;
    if constexpr (AM == 0) {
      s = p.a0 + (size_t)row * p.lda + col;
    } else if constexpr (AM == 2) {
      s = (col < 512) ? (p.a0 + (size_t)row * 512 + col)
                      : (p.a1 + (size_t)row * 1024 + (col - 512));
    } else {
      s = (col < 512)  ? (p.a0 + (size_t)row * 512 + col)
        : (col < 1536) ? (p.a1 + (size_t)row * 1024 + (col - 512))
                       : (p.a2 + (size_t)row * 1024 + (col - 1536));
    }
    f32x4 x0 = *(const f32x4*)(s);
    f32x4 x1 = *(const f32x4*)(s + 4);
    u16x8 r;
    r[0] = f2bf(x0.x); r[1] = f2bf(x0.y); r[2] = f2bf(x0.z); r[3] = f2bf(x0.w);
    r[4] = f2bf(x1.x); r[5] = f2bf(x1.y); r[6] = f2bf(x1.z); r[7] = f2bf(x1.w);
    return r;
  }
}

// BMODE: 0 = f32 (b0, ldb); 1 = KV: n<1024 -> Wk(ld1088) else Wv(ld1088);
//        2 = concat-k [W_ih(512)|W_hh(1024)|W_ac(1024)]
template<int BMODE>
__device__ __forceinline__ u16x8 load_b8(const GP& p, int n, int k) {
  const float* s;
  if constexpr (BMODE == 0) {
    s = p.b0 + (size_t)n * p.ldb + k;
  } else if constexpr (BMODE == 1) {
    s = (n < 1024) ? (p.b0 + (size_t)n * 1088 + k)
                   : (p.b1 + (size_t)(n - 1024) * 1088 + k);
  } else {
    s = (k < 512)  ? (p.b0 + (size_t)n * 512 + k)
      : (k < 1536) ? (p.b1 + (size_t)n * 1024 + (k - 512))
                   : (p.b2 + (size_t)n * 1024 + (k - 1536));
  }
  f32x4 x0 = *(const f32x4*)(s);
  f32x4 x1 = *(const f32x4*)(s + 4);
  u16x8 r;
  r[0] = f2bf(x0.x); r[1] = f2bf(x0.y); r[2] = f2bf(x0.z); r[3] = f2bf(x0.w);
  r[4] = f2bf(x1.x); r[5] = f2bf(x1.y); r[6] = f2bf(x1.z); r[7] = f2bf(x1.w);
  return r;
}

// 128x128 tile, BK=64, 4 waves (each 64x64), mfma_f32_16x16x32_bf16.
// LDS XOR-swizzle on 16B chunks: slot (r,p8) holds logical chunk p8^(r&7).
template<int AM, int BMODE, int ACT, int PEB, int EPI>
__global__ __launch_bounds__(256)
void gemm_k(GP p) {
  __shared__ unsigned short sA[128 * 64];
  __shared__ unsigned short sB[128 * 64];
  const int tid = threadIdx.x;
  const int lane = tid & 63;
  const int wid = tid >> 6;
  const int col0 = blockIdx.x * 128;  // n
  const int row0 = blockIdx.y * 128;  // m
  const int wr = (wid >> 1) * 64, wc = (wid & 1) * 64;
  const int g = lane >> 4, lr = lane & 15;

  f32x4 acc[4][4] = {};

  const int r_s = tid >> 3;
  const int p8 = tid & 7;

  for (int kb = 0; kb < p.K; kb += 64) {
    __syncthreads();
#pragma unroll
    for (int pass = 0; pass < 4; ++pass) {
      int r = r_s + pass * 32;
      int c8 = p8 ^ (r & 7);
      u16x8 av = load_a8<AM>(p, row0 + r, kb + c8 * 8);
      *(u16x8*)(&sA[(r * 8 + p8) * 8]) = av;
      u16x8 bv = load_b8<BMODE>(p, col0 + r, kb + c8 * 8);
      *(u16x8*)(&sB[(r * 8 + p8) * 8]) = bv;
    }
    __syncthreads();
#pragma unroll
    for (int kk = 0; kk < 64; kk += 32) {
      s16x8 af[4], bfr[4];
#pragma unroll
      for (int i = 0; i < 4; ++i) {
        int ar = wr + i * 16 + lr;
        int ac8 = (kk >> 3) + g;
        af[i] = *(const s16x8*)(&sA[(ar * 8 + (ac8 ^ (ar & 7))) * 8]);
        int br = wc + i * 16 + lr;
        bfr[i] = *(const s16x8*)(&sB[(br * 8 + (ac8 ^ (br & 7))) * 8]);
      }
#pragma unroll
      for (int mi = 0; mi < 4; ++mi)
#pragma unroll
        for (int ni = 0; ni < 4; ++ni)
          acc[mi][ni] = __builtin_amdgcn_mfma_f32_16x16x32_bf16(
              af[mi], bfr[ni], acc[mi][ni], 0, 0, 0);
    }
  }

  // C/D layout (m89-verified): col = lane&15, row = (lane>>4)*4 + reg
#pragma unroll
  for (int mi = 0; mi < 4; ++mi) {
#pragma unroll
    for (int ni = 0; ni < 4; ++ni) {
#pragma unroll
      for (int rg = 0; rg < 4; ++rg) {
        int rr = row0 + wr + mi * 16 + g * 4 + rg;
        int cc = col0 + wc + ni * 16 + lr;
        float v = acc[mi][ni][rg];
        if constexpr (PEB) v += p.peb[(size_t)(rr >> 9) * p.N + cc];
        else v += p.bias[cc];
        if constexpr (ACT) v = eluf(v);
        if constexpr (EPI == 0) {
          p.of[(size_t)rr * p.N + cc] = v;
        } else if constexpr (EPI == 1) {
          p.ob[(size_t)rr * p.N + cc] = f2bf(v);
        } else if constexpr (EPI == 2) {
          if (cc < 1024) p.ob[(size_t)rr * 1024 + cc] = f2bf(v);
          else           p.ob2[(size_t)rr * 1024 + (cc - 1024)] = f2bf(v);
        } else {
          v = v * p.bnS[cc] + p.bnT[cc];
          p.of[(size_t)rr * p.N + cc] = v;
        }
      }
    }
  }
}

// peb[w][n] (n<1024: K-proj, else V-proj): base bias + sum_p pe[w,p]*W[n,1024+p]
__global__ __launch_bounds__(256)
void prep_peb(const float* __restrict__ Wk, const float* __restrict__ Wv,
              const float* __restrict__ bk, const float* __restrict__ bv,
              float* __restrict__ peb) {
  int idx = blockIdx.x * 256 + threadIdx.x;  // [0, 65536)
  int w = idx >> 11, n = idx & 2047;
  const float* Wrow =
      ((n < 1024) ? (Wk + (size_t)n * 1088) : (Wv + (size_t)(n - 1024) * 1088)) + 1024;
  float acc = (n < 1024) ? bk[n] : bv[n - 1024];
  const float c0 = logf(10000.f) / 64.f;
#pragma unroll
  for (int j = 0; j < 32; ++j) {
    float ang = (float)w * expf(-(2.f * j) * c0);
    acc += sinf(ang) * Wrow[2 * j] + cosf(ang) * Wrow[2 * j + 1];
  }
  peb[idx] = acc;
}

__global__ void prep_misc(const float* b_ih, const float* b_ac,
                          const float* g1, const float* be1, const float* m1, const float* v1,
                          const float* g2, const float* be2, const float* m2, const float* v2,
                          float* bias6, float* s1, float* t1, float* s2, float* t2) {
  int i = blockIdx.x * 256 + threadIdx.x;
  if (i < 4096) bias6[i] = b_ih[i] + b_ac[i];
  if (i < 1024) {
    float sa = g1[i] * rsqrtf(v1[i] + 1e-5f);
    s1[i] = sa; t1[i] = be1[i] - m1[i] * sa;
    float sp = g2[i] * rsqrtf(v2[i] + 1e-5f);
    s2[i] = sp; t2[i] = be2[i] - m2[i] * sp;
  }
}

// one wave per (b,h): lanes (w,half) for scores, lane=d for PV
__global__ __launch_bounds__(256)
void attn_k(const float* __restrict__ Q, const unsigned short* __restrict__ Kb,
            const unsigned short* __restrict__ Vb, unsigned short* __restrict__ ctx) {
  int lane = threadIdx.x & 63;
  int gw = (blockIdx.x << 2) + (threadIdx.x >> 6);
  int b = gw >> 4, h = gw & 15;
  int w = lane & 31, half = lane >> 5;
  const unsigned short* Krow = Kb + (size_t)(w * 512 + b) * 1024 + h * 64 + half * 32;
  const float* Qp = Q + (size_t)b * 1024 + h * 64 + half * 32;
  float s = 0.f;
#pragma unroll
  for (int j = 0; j < 32; j += 8) {
    u16x8 kv = *(const u16x8*)(Krow + j);
    f32x4 q0 = *(const f32x4*)(Qp + j);
    f32x4 q1 = *(const f32x4*)(Qp + j + 4);
    s += q0.x * bf2f(kv[0]) + q0.y * bf2f(kv[1]) + q0.z * bf2f(kv[2]) + q0.w * bf2f(kv[3])
       + q1.x * bf2f(kv[4]) + q1.y * bf2f(kv[5]) + q1.z * bf2f(kv[6]) + q1.w * bf2f(kv[7]);
  }
  s += __shfl_xor(s, 32);
  s *= 0.125f;  // 1/sqrt(64)
  float mx = s;
#pragma unroll
  for (int off = 16; off; off >>= 1) mx = fmaxf(mx, __shfl_xor(mx, off));
  float e = expf(s - mx);
  float sum = e;
#pragma unroll
  for (int off = 16; off; off >>= 1) sum += __shfl_xor(sum, off);
  float pr = e / sum;
  float c = 0.f;
#pragma unroll 8
  for (int w2 = 0; w2 < 32; ++w2) {
    float pw = __shfl(pr, w2);
    c += pw * bf2f(Vb[(size_t)(w2 * 512 + b) * 1024 + h * 64 + lane]);
  }
  ctx[(size_t)b * 1024 + h * 64 + lane] = f2bf(c);
}

__global__ __launch_bounds__(256)
void final_k(const float* __restrict__ pre, const float* __restrict__ pcell,
             const float* __restrict__ s2, const float* __restrict__ t2,
             float* __restrict__ out) {
  int i = blockIdx.x * 256 + threadIdx.x;  // [0, 524288)
  int j = i & 1023;
  const float* pm = pre + (size_t)(i >> 10) * 4096;
  float iv = tanhf(pm[j]);
  float f  = sigf(pm[1024 + j]);
  float ii = sigf(pm[2048 + j]);
  float o  = sigf(pm[3072 + j]);
  float cell = iv * ii + pcell[i] * f;
  float ec = cell > 0.f ? cell : expf(cell) - 1.f;
  out[i] = (o * ec) * s2[j] + t2[j];
}

extern "C" void kernel_launch(void* const* d_in, const int* in_sizes, int n_in,
                              void* d_out, int out_size, void* d_ws, size_t ws_size,
                              hipStream_t stream) {
  (void)in_sizes; (void)n_in; (void)out_size; (void)ws_size;
  const float* x     = (const float*)d_in[0];
  const float* ph    = (const float*)d_in[1];
  const float* pcell = (const float*)d_in[2];
  const float* pcs   = (const float*)d_in[3];
  const float* W_ih  = (const float*)d_in[4];
  const float* b_ih  = (const float*)d_in[5];
  const float* W_hh  = (const float*)d_in[6];
  const float* W_q   = (const float*)d_in[7];
  const float* b_q   = (const float*)d_in[8];
  const float* W_ac  = (const float*)d_in[9];
  const float* b_ac  = (const float*)d_in[10];
  const float* Wq_a  = (const float*)d_in[11];
  const float* bq_a  = (const float*)d_in[12];
  const float* Wk_a  = (const float*)d_in[13];
  const float* bk_a  = (const float*)d_in[14];
  const float* Wv_a  = (const float*)d_in[15];
  const float* bv_a  = (const float*)d_in[16];
  const float* Wo_a  = (const float*)d_in[17];
  const float* bo_a  = (const float*)d_in[18];
  const float* g1    = (const float*)d_in[19];
  const float* be1   = (const float*)d_in[20];
  const float* m1    = (const float*)d_in[21];
  const float* v1    = (const float*)d_in[22];
  const float* g2    = (const float*)d_in[23];
  const float* be2   = (const float*)d_in[24];
  const float* m2    = (const float*)d_in[25];
  const float* v2    = (const float*)d_in[26];

  char* wp = (char*)d_ws;
  auto alloc = [&](size_t bytes) {
    char* r = wp; wp += (bytes + 255) & ~(size_t)255; return r;
  };
  unsigned short* q_bf  = (unsigned short*)alloc((size_t)512 * 1024 * 2);
  float*          Qf    = (float*)alloc((size_t)512 * 1024 * 4);
  unsigned short* K_bf  = (unsigned short*)alloc((size_t)16384 * 1024 * 2);
  unsigned short* V_bf  = (unsigned short*)alloc((size_t)16384 * 1024 * 2);
  unsigned short* ctxbf = (unsigned short*)alloc((size_t)512 * 1024 * 2);
  float*          attnf = (float*)alloc((size_t)512 * 1024 * 4);
  float*          pre   = (float*)alloc((size_t)512 * 4096 * 4);
  float*          peb   = (float*)alloc((size_t)32 * 2048 * 4);
  float*          bias6 = (float*)alloc((size_t)4096 * 4);
  float*          s1    = (float*)alloc((size_t)1024 * 4);
  float*          t1    = (float*)alloc((size_t)1024 * 4);
  float*          s2    = (float*)alloc((size_t)1024 * 4);
  float*          t2    = (float*)alloc((size_t)1024 * 4);

  prep_peb<<<256, 256, 0, stream>>>(Wk_a, Wv_a, bk_a, bv_a, peb);
  prep_misc<<<16, 256, 0, stream>>>(b_ih, b_ac, g1, be1, m1, v1, g2, be2, m2, v2,
                                    bias6, s1, t1, s2, t2);

  // G1: q = elu([x|ph] @ W_q^T + b_q) -> q_bf (512x1024)
  {
    GP p = {};
    p.a0 = x; p.a1 = ph;
    p.b0 = W_q; p.ldb = 1536;
    p.bias = b_q; p.ob = q_bf; p.N = 1024; p.K = 1536;
    gemm_k<2, 0, 1, 0, 1><<<dim3(8, 4), 256, 0, stream>>>(p);
  }
  // G2: Q = q @ Wq_a^T + bq_a -> Qf (512x1024 f32)
  {
    GP p = {};
    p.ab = q_bf; p.lda = 1024;
    p.b0 = Wq_a; p.ldb = 1024;
    p.bias = bq_a; p.of = Qf; p.N = 1024; p.K = 1024;
    gemm_k<1, 0, 0, 0, 0><<<dim3(8, 4), 256, 0, stream>>>(p);
  }
  // G34: K/V = elu(past_cells @ [Wk|Wv]^T + peb) -> K_bf, V_bf (rows = w*512+b)
  {
    GP p = {};
    p.a0 = pcs; p.lda = 1024;
    p.b0 = Wk_a; p.b1 = Wv_a;
    p.peb = peb; p.ob = K_bf; p.ob2 = V_bf; p.N = 2048; p.K = 1024;
    gemm_k<0, 1, 1, 1, 2><<<dim3(16, 128), 256, 0, stream>>>(p);
  }
  attn_k<<<2048, 256, 0, stream>>>(Qf, K_bf, V_bf, ctxbf);
  // G5: attn = bn(elu(ctx @ Wo_a^T + bo_a)) -> attnf (f32)
  {
    GP p = {};
    p.ab = ctxbf; p.lda = 1024;
    p.b0 = Wo_a; p.ldb = 1024;
    p.bias = bo_a; p.bnS = s1; p.bnT = t1; p.of = attnf; p.N = 1024; p.K = 1024;
    gemm_k<1, 0, 1, 0, 3><<<dim3(8, 4), 256, 0, stream>>>(p);
  }
  // G6: pre = [x|ph|attn] @ [W_ih|W_hh|W_ac]^T + (b_ih + b_ac) -> pre (512x4096)
  {
    GP p = {};
    p.a0 = x; p.a1 = ph; p.a2 = attnf;
    p.b0 = W_ih; p.b1 = W_hh; p.b2 = W_ac;
    p.bias = bias6; p.of = pre; p.N = 4096; p.K = 2560;
    gemm_k<3, 2, 0, 0, 0><<<dim3(32, 4), 256, 0, stream>>>(p);
  }
  final_k<<<2048, 256, 0, stream>>>(pre, pcell, s2, t2, (float*)d_out);
}

// Round 2
// 415.396 us; speedup vs baseline: 1.7828x; 1.7828x over previous
//
#include <hip/hip_runtime.h>
#include <hip/hip_bf16.h>

typedef __attribute__((ext_vector_type(8))) short s16x8;
typedef __attribute__((ext_vector_type(8))) unsigned short u16x8;
typedef __attribute__((ext_vector_type(4))) float f32x4;

__device__ __forceinline__ float bf2f(unsigned short u) {
  union { unsigned int i; float f; } v; v.i = ((unsigned int)u) << 16; return v.f;
}
__device__ __forceinline__ unsigned short f2bf(float f) {
  union { float f; unsigned int i; } v; v.f = f;
  unsigned int u = v.i;
  unsigned int r = (u + 0x7fffu + ((u >> 16) & 1u)) >> 16;
  return (unsigned short)r;
}
__device__ __forceinline__ float eluf(float x) { return x > 0.f ? x : expf(x) - 1.f; }
__device__ __forceinline__ float sigf(float x) { return 1.f / (1.f + expf(-x)); }

__device__ __forceinline__ void gl_lds16(const unsigned short* g, unsigned short* l) {
  __builtin_amdgcn_global_load_lds(
      (const __attribute__((address_space(1))) void*)g,
      (__attribute__((address_space(3))) void*)l, 16, 0, 0);
}

// ---------------------------------------------------------------------------
// cast_all: f32 -> bf16 for every GEMM operand, stored chunk-XOR-swizzled:
//   stored col = col ^ ((row&7)<<3)   (involution, within each 64-col block)
// One thread per 16B chunk (8 elems).
// ---------------------------------------------------------------------------
__global__ __launch_bounds__(256)
void cast_all(const float* __restrict__ pcs,
              const float* __restrict__ W_ih, const float* __restrict__ W_hh,
              const float* __restrict__ W_ac, const float* __restrict__ W_q,
              const float* __restrict__ Wq_a, const float* __restrict__ Wo_a,
              const float* __restrict__ Wk_a, const float* __restrict__ Wv_a,
              const float* __restrict__ x, const float* __restrict__ ph,
              unsigned short* __restrict__ A_pc, unsigned short* __restrict__ W6,
              unsigned short* __restrict__ Wq, unsigned short* __restrict__ Wqa,
              unsigned short* __restrict__ Woa, unsigned short* __restrict__ Wkv,
              unsigned short* __restrict__ A6) {
  int c = blockIdx.x * 256 + threadIdx.x;
  const float* src; unsigned short* dst; int row, col, ldd;
  if (c < 2097152) {                       // A_pc: past_cells 16384x1024
    row = c >> 7; col = (c & 127) << 3;
    src = pcs + (size_t)row * 1024 + col; dst = A_pc; ldd = 1024;
  } else if (c < 3407872) {                // W6: [W_ih|W_hh|W_ac] 4096x2560
    int i = c - 2097152; row = i / 320; col = (i - row * 320) << 3;
    dst = W6; ldd = 2560;
    src = (col < 512)  ? W_ih + (size_t)row * 512 + col
        : (col < 1536) ? W_hh + (size_t)row * 1024 + (col - 512)
                       : W_ac + (size_t)row * 1024 + (col - 1536);
  } else if (c < 3604480) {                // Wq: 1024x1536
    int i = c - 3407872; row = i / 192; col = (i - row * 192) << 3;
    src = W_q + (size_t)row * 1536 + col; dst = Wq; ldd = 1536;
  } else if (c < 3735552) {                // Wqa: 1024x1024
    int i = c - 3604480; row = i >> 7; col = (i & 127) << 3;
    src = Wq_a + (size_t)row * 1024 + col; dst = Wqa; ldd = 1024;
  } else if (c < 3866624) {                // Woa: 1024x1024
    int i = c - 3735552; row = i >> 7; col = (i & 127) << 3;
    src = Wo_a + (size_t)row * 1024 + col; dst = Woa; ldd = 1024;
  } else if (c < 4128768) {                // Wkv: 2048x1024 (from 1088-ld)
    int i = c - 3866624; row = i >> 7; col = (i & 127) << 3;
    src = (row < 1024) ? Wk_a + (size_t)row * 1088 + col
                       : Wv_a + (size_t)(row - 1024) * 1088 + col;
    dst = Wkv; ldd = 1024;
  } else {                                 // A6 cols 0..1536: [x|ph] 512x1536
    int i = c - 4128768; row = i / 192; col = (i - row * 192) << 3;
    src = (col < 512) ? x + (size_t)row * 512 + col
                      : ph + (size_t)row * 1024 + (col - 512);
    dst = A6; ldd = 2560;
  }
  f32x4 v0 = *(const f32x4*)src;
  f32x4 v1 = *(const f32x4*)(src + 4);
  u16x8 r;
  r[0] = f2bf(v0.x); r[1] = f2bf(v0.y); r[2] = f2bf(v0.z); r[3] = f2bf(v0.w);
  r[4] = f2bf(v1.x); r[5] = f2bf(v1.y); r[6] = f2bf(v1.z); r[7] = f2bf(v1.w);
  int sc = col ^ ((row & 7) << 3);
  *(u16x8*)(dst + (size_t)row * ldd + sc) = r;
}

// ---------------------------------------------------------------------------
// m97-structure GEMM: pre-swizzled bf16 A[M][lda], B[N][ldb] (B^T layout),
// global_load_lds staging (linear LDS), swizzled ds_read_b128 fragments.
// EPI: 0=f32 linear; 1=bf16 swizzled (ld=N); 2=K/V split linear bf16;
//      3=BN + bf16 swizzled into A6 at col offset 1536 (ld=2560)
// ---------------------------------------------------------------------------
struct GP2 {
  const unsigned short* A; long lda;
  const unsigned short* B; long ldb;
  const float* bias; const float* peb;
  const float* bnS; const float* bnT;
  float* of; unsigned short* ob; unsigned short* ob2;
  int N, K;
};

template<int BM, int BN, int EPI, int PEB, int ACT>
__global__ __launch_bounds__(256)
void gemm2(GP2 p) {
  __shared__ unsigned short sA[BM * 64];
  __shared__ unsigned short sB[BN * 64];
  const int tid = threadIdx.x, lane = tid & 63, wid = tid >> 6;
  const int col0 = blockIdx.x * BN, row0 = blockIdx.y * BM;
  constexpr int WRS = BM / 2, WCS = BN / 2;
  constexpr int MI = WRS / 16, NI = WCS / 16;
  const int wr = (wid >> 1) * WRS, wc = (wid & 1) * WCS;
  const int g = lane >> 4, lr = lane & 15;
  f32x4 acc[MI][NI] = {};

  for (int kb = 0; kb < p.K; kb += 64) {
    __syncthreads();
#pragma unroll
    for (int ps = 0; ps < (BM * 8) / 256; ++ps) {
      int chunk = ps * 256 + wid * 64 + lane;
      int r = chunk >> 3, c8 = chunk & 7;
      gl_lds16(p.A + (size_t)(row0 + r) * p.lda + kb + c8 * 8, &sA[chunk * 8]);
    }
#pragma unroll
    for (int ps = 0; ps < (BN * 8) / 256; ++ps) {
      int chunk = ps * 256 + wid * 64 + lane;
      int r = chunk >> 3, c8 = chunk & 7;
      gl_lds16(p.B + (size_t)(col0 + r) * p.ldb + kb + c8 * 8, &sB[chunk * 8]);
    }
    __syncthreads();
#pragma unroll
    for (int kk = 0; kk < 64; kk += 32) {
      s16x8 af[MI], bf_[NI];
#pragma unroll
      for (int i = 0; i < MI; ++i) {
        int ar = wr + i * 16 + lr;
        int sl = ((kk >> 3) + g) ^ (ar & 7);
        af[i] = *(const s16x8*)(&sA[(ar * 8 + sl) * 8]);
      }
#pragma unroll
      for (int i = 0; i < NI; ++i) {
        int br = wc + i * 16 + lr;
        int sl = ((kk >> 3) + g) ^ (br & 7);
        bf_[i] = *(const s16x8*)(&sB[(br * 8 + sl) * 8]);
      }
#pragma unroll
      for (int mi = 0; mi < MI; ++mi)
#pragma unroll
        for (int ni = 0; ni < NI; ++ni)
          acc[mi][ni] = __builtin_amdgcn_mfma_f32_16x16x32_bf16(
              af[mi], bf_[ni], acc[mi][ni], 0, 0, 0);
    }
  }

  // C/D layout (m89): col = lane&15, row = (lane>>4)*4 + reg
#pragma unroll
  for (int mi = 0; mi < MI; ++mi) {
#pragma unroll
    for (int ni = 0; ni < NI; ++ni) {
#pragma unroll
      for (int rg = 0; rg < 4; ++rg) {
        int rr = row0 + wr + mi * 16 + g * 4 + rg;
        int cc = col0 + wc + ni * 16 + lr;
        float v = acc[mi][ni][rg];
        if constexpr (PEB) v += p.peb[(size_t)(rr >> 9) * 2048 + cc];
        else v += p.bias[cc];
        if constexpr (ACT) v = eluf(v);
        if constexpr (EPI == 0) {
          p.of[(size_t)rr * p.N + cc] = v;
        } else if constexpr (EPI == 1) {
          p.ob[(size_t)rr * p.N + (cc ^ ((rr & 7) << 3))] = f2bf(v);
        } else if constexpr (EPI == 2) {
          if (cc < 1024) p.ob[(size_t)rr * 1024 + cc] = f2bf(v);
          else           p.ob2[(size_t)rr * 1024 + (cc - 1024)] = f2bf(v);
        } else {
          v = v * p.bnS[cc] + p.bnT[cc];
          p.ob[(size_t)rr * 2560 + ((1536 + cc) ^ ((rr & 7) << 3))] = f2bf(v);
        }
      }
    }
  }
}

// peb[w][n] (n<1024: K-proj, else V): base bias + sum_p pe[w,p]*W[n,1024+p]
__global__ __launch_bounds__(256)
void prep_peb(const float* __restrict__ Wk, const float* __restrict__ Wv,
              const float* __restrict__ bk, const float* __restrict__ bv,
              float* __restrict__ peb) {
  int idx = blockIdx.x * 256 + threadIdx.x;  // [0, 65536)
  int w = idx >> 11, n = idx & 2047;
  const float* Wrow =
      ((n < 1024) ? (Wk + (size_t)n * 1088) : (Wv + (size_t)(n - 1024) * 1088)) + 1024;
  float acc = (n < 1024) ? bk[n] : bv[n - 1024];
  const float c0 = logf(10000.f) / 64.f;
#pragma unroll
  for (int j = 0; j < 32; ++j) {
    float ang = (float)w * __expf(-(2.f * j) * c0);
    acc += __sinf(ang) * Wrow[2 * j] + __cosf(ang) * Wrow[2 * j + 1];
  }
  peb[idx] = acc;
}

__global__ void prep_misc(const float* b_ih, const float* b_ac,
                          const float* g1, const float* be1, const float* m1, const float* v1,
                          const float* g2, const float* be2, const float* m2, const float* v2,
                          float* bias6, float* s1, float* t1, float* s2, float* t2) {
  int i = blockIdx.x * 256 + threadIdx.x;
  if (i < 4096) bias6[i] = b_ih[i] + b_ac[i];
  if (i < 1024) {
    float sa = g1[i] * rsqrtf(v1[i] + 1e-5f);
    s1[i] = sa; t1[i] = be1[i] - m1[i] * sa;
    float sp = g2[i] * rsqrtf(v2[i] + 1e-5f);
    s2[i] = sp; t2[i] = be2[i] - m2[i] * sp;
  }
}

// one wave per (b,h); ctx written bf16 SWIZZLED (row=b) for G5's A operand
__global__ __launch_bounds__(256)
void attn_k(const float* __restrict__ Q, const unsigned short* __restrict__ Kb,
            const unsigned short* __restrict__ Vb, unsigned short* __restrict__ ctx) {
  int lane = threadIdx.x & 63;
  int gw = (blockIdx.x << 2) + (threadIdx.x >> 6);
  int b = gw >> 4, h = gw & 15;
  int w = lane & 31, half = lane >> 5;
  const unsigned short* Krow = Kb + (size_t)(w * 512 + b) * 1024 + h * 64 + half * 32;
  const float* Qp = Q + (size_t)b * 1024 + h * 64 + half * 32;
  float s = 0.f;
#pragma unroll
  for (int j = 0; j < 32; j += 8) {
    u16x8 kv = *(const u16x8*)(Krow + j);
    f32x4 q0 = *(const f32x4*)(Qp + j);
    f32x4 q1 = *(const f32x4*)(Qp + j + 4);
    s += q0.x * bf2f(kv[0]) + q0.y * bf2f(kv[1]) + q0.z * bf2f(kv[2]) + q0.w * bf2f(kv[3])
       + q1.x * bf2f(kv[4]) + q1.y * bf2f(kv[5]) + q1.z * bf2f(kv[6]) + q1.w * bf2f(kv[7]);
  }
  s += __shfl_xor(s, 32);
  s *= 0.125f;  // 1/sqrt(64)
  float mx = s;
#pragma unroll
  for (int off = 16; off; off >>= 1) mx = fmaxf(mx, __shfl_xor(mx, off));
  float e = expf(s - mx);
  float sum = e;
#pragma unroll
  for (int off = 16; off; off >>= 1) sum += __shfl_xor(sum, off);
  float pr = e / sum;
  float c = 0.f;
#pragma unroll 8
  for (int w2 = 0; w2 < 32; ++w2) {
    float pw = __shfl(pr, w2);
    c += pw * bf2f(Vb[(size_t)(w2 * 512 + b) * 1024 + h * 64 + lane]);
  }
  ctx[(size_t)b * 1024 + ((h * 64 + lane) ^ ((b & 7) << 3))] = f2bf(c);
}

__global__ __launch_bounds__(256)
void final_k(const float* __restrict__ pre, const float* __restrict__ pcell,
             const float* __restrict__ s2, const float* __restrict__ t2,
             float* __restrict__ out) {
  int i = blockIdx.x * 256 + threadIdx.x;  // [0, 524288)
  int j = i & 1023;
  const float* pm = pre + (size_t)(i >> 10) * 4096;
  float iv = tanhf(pm[j]);
  float f  = sigf(pm[1024 + j]);
  float ii = sigf(pm[2048 + j]);
  float o  = sigf(pm[3072 + j]);
  float cell = iv * ii + pcell[i] * f;
  float ec = cell > 0.f ? cell : expf(cell) - 1.f;
  out[i] = (o * ec) * s2[j] + t2[j];
}

extern "C" void kernel_launch(void* const* d_in, const int* in_sizes, int n_in,
                              void* d_out, int out_size, void* d_ws, size_t ws_size,
                              hipStream_t stream) {
  (void)in_sizes; (void)n_in; (void)out_size; (void)ws_size;
  const float* x     = (const float*)d_in[0];
  const float* ph    = (const float*)d_in[1];
  const float* pcell = (const float*)d_in[2];
  const float* pcs   = (const float*)d_in[3];
  const float* W_ih  = (const float*)d_in[4];
  const float* b_ih  = (const float*)d_in[5];
  const float* W_hh  = (const float*)d_in[6];
  const float* W_q   = (const float*)d_in[7];
  const float* b_q   = (const float*)d_in[8];
  const float* W_ac  = (const float*)d_in[9];
  const float* b_ac  = (const float*)d_in[10];
  const float* Wq_a  = (const float*)d_in[11];
  const float* bq_a  = (const float*)d_in[12];
  const float* Wk_a  = (const float*)d_in[13];
  const float* bk_a  = (const float*)d_in[14];
  const float* Wv_a  = (const float*)d_in[15];
  const float* bv_a  = (const float*)d_in[16];
  const float* Wo_a  = (const float*)d_in[17];
  const float* bo_a  = (const float*)d_in[18];
  const float* g1    = (const float*)d_in[19];
  const float* be1   = (const float*)d_in[20];
  const float* m1    = (const float*)d_in[21];
  const float* v1    = (const float*)d_in[22];
  const float* g2    = (const float*)d_in[23];
  const float* be2   = (const float*)d_in[24];
  const float* m2    = (const float*)d_in[25];
  const float* v2    = (const float*)d_in[26];

  char* wp = (char*)d_ws;
  auto alloc = [&](size_t bytes) {
    char* r = wp; wp += (bytes + 255) & ~(size_t)255; return r;
  };
  unsigned short* A_pc  = (unsigned short*)alloc((size_t)16384 * 1024 * 2);
  unsigned short* W6    = (unsigned short*)alloc((size_t)4096 * 2560 * 2);
  unsigned short* Wq    = (unsigned short*)alloc((size_t)1024 * 1536 * 2);
  unsigned short* Wqa   = (unsigned short*)alloc((size_t)1024 * 1024 * 2);
  unsigned short* Woa   = (unsigned short*)alloc((size_t)1024 * 1024 * 2);
  unsigned short* Wkv   = (unsigned short*)alloc((size_t)2048 * 1024 * 2);
  unsigned short* A6    = (unsigned short*)alloc((size_t)512 * 2560 * 2);
  unsigned short* q_bf  = (unsigned short*)alloc((size_t)512 * 1024 * 2);
  float*          Qf    = (float*)alloc((size_t)512 * 1024 * 4);
  unsigned short* K_bf  = (unsigned short*)alloc((size_t)16384 * 1024 * 2);
  unsigned short* V_bf  = (unsigned short*)alloc((size_t)16384 * 1024 * 2);
  unsigned short* ctxbf = (unsigned short*)alloc((size_t)512 * 1024 * 2);
  float*          pre   = (float*)alloc((size_t)512 * 4096 * 4);
  float*          peb   = (float*)alloc((size_t)32 * 2048 * 4);
  float*          bias6 = (float*)alloc((size_t)4096 * 4);
  float*          s1    = (float*)alloc((size_t)1024 * 4);
  float*          t1    = (float*)alloc((size_t)1024 * 4);
  float*          s2    = (float*)alloc((size_t)1024 * 4);
  float*          t2    = (float*)alloc((size_t)1024 * 4);

  cast_all<<<16512, 256, 0, stream>>>(pcs, W_ih, W_hh, W_ac, W_q, Wq_a, Wo_a,
                                      Wk_a, Wv_a, x, ph,
                                      A_pc, W6, Wq, Wqa, Woa, Wkv, A6);
  prep_peb<<<256, 256, 0, stream>>>(Wk_a, Wv_a, bk_a, bv_a, peb);
  prep_misc<<<16, 256, 0, stream>>>(b_ih, b_ac, g1, be1, m1, v1, g2, be2, m2, v2,
                                    bias6, s1, t1, s2, t2);

  // G34: K/V = elu(past_cells @ [Wk|Wv]^T + peb) -> K_bf, V_bf (linear)
  {
    GP2 p = {};
    p.A = A_pc; p.lda = 1024; p.B = Wkv; p.ldb = 1024;
    p.peb = peb; p.ob = K_bf; p.ob2 = V_bf; p.N = 2048; p.K = 1024;
    gemm2<128, 128, 2, 1, 1><<<dim3(16, 128), 256, 0, stream>>>(p);
  }
  // G1: q = elu([x|ph] @ W_q^T + b_q) -> q_bf (swizzled)
  {
    GP2 p = {};
    p.A = A6; p.lda = 2560; p.B = Wq; p.ldb = 1536;
    p.bias = b_q; p.ob = q_bf; p.N = 1024; p.K = 1536;
    gemm2<64, 64, 1, 0, 1><<<dim3(16, 8), 256, 0, stream>>>(p);
  }
  // G2: Q = q @ Wq_a^T + bq_a -> Qf (f32 linear)
  {
    GP2 p = {};
    p.A = q_bf; p.lda = 1024; p.B = Wqa; p.ldb = 1024;
    p.bias = bq_a; p.of = Qf; p.N = 1024; p.K = 1024;
    gemm2<64, 64, 0, 0, 0><<<dim3(16, 8), 256, 0, stream>>>(p);
  }
  attn_k<<<2048, 256, 0, stream>>>(Qf, K_bf, V_bf, ctxbf);
  // G5: attn = bn(elu(ctx @ Wo_a^T + bo_a)) -> A6 cols 1536.. (bf16 swizzled)
  {
    GP2 p = {};
    p.A = ctxbf; p.lda = 1024; p.B = Woa; p.ldb = 1024;
    p.bias = bo_a; p.bnS = s1; p.bnT = t1; p.ob = A6; p.N = 1024; p.K = 1024;
    gemm2<64, 64, 3, 0, 1><<<dim3(16, 8), 256, 0, stream>>>(p);
  }
  // G6: pre = [x|ph|attn] @ [W_ih|W_hh|W_ac]^T + bias6 -> pre (f32)
  {
    GP2 p = {};
    p.A = A6; p.lda = 2560; p.B = W6; p.ldb = 2560;
    p.bias = bias6; p.of = pre; p.N = 4096; p.K = 2560;
    gemm2<128, 128, 0, 0, 0><<<dim3(32, 4), 256, 0, stream>>>(p);
  }
  final_k<<<2048, 256, 0, stream>>>(pre, pcell, s2, t2, (float*)d_out);
}

// Round 3
// 381.149 us; speedup vs baseline: 1.9430x; 1.0899x over previous
//
#include <hip/hip_runtime.h>
#include <hip/hip_bf16.h>

typedef __attribute__((ext_vector_type(8))) short s16x8;
typedef __attribute__((ext_vector_type(8))) unsigned short u16x8;
typedef __attribute__((ext_vector_type(4))) float f32x4;

__device__ __forceinline__ float bf2f(unsigned short u) {
  union { unsigned int i; float f; } v; v.i = ((unsigned int)u) << 16; return v.f;
}
__device__ __forceinline__ unsigned short f2bf(float f) {
  union { float f; unsigned int i; } v; v.f = f;
  unsigned int u = v.i;
  unsigned int r = (u + 0x7fffu + ((u >> 16) & 1u)) >> 16;
  return (unsigned short)r;
}
__device__ __forceinline__ float eluf(float x) { return x > 0.f ? x : __expf(x) - 1.f; }
__device__ __forceinline__ float sigf(float x) { return 1.f / (1.f + __expf(-x)); }
__device__ __forceinline__ float tanhfast(float x) {
  float ax = fminf(fabsf(x), 15.f);
  float e2 = __expf(2.f * ax);
  float t = (e2 - 1.f) / (e2 + 1.f);
  return x < 0.f ? -t : t;
}

__device__ __forceinline__ void gl_lds16(const unsigned short* g, unsigned short* l) {
  __builtin_amdgcn_global_load_lds(
      (const __attribute__((address_space(1))) void*)g,
      (__attribute__((address_space(3))) void*)l, 16, 0, 0);
}

// ---------------------------------------------------------------------------
// cast_all: f32 -> bf16 for every GEMM operand, stored chunk-XOR-swizzled:
//   stored col = col ^ ((row&7)<<3). Also computes peb + bias/BN prep tails.
// ---------------------------------------------------------------------------
struct CP {
  const float *pcs, *W_ih, *W_hh, *W_ac, *W_q, *Wq_a, *Wo_a, *Wk_a, *Wv_a, *x, *ph;
  const float *b_ih, *b_ac, *bk, *bv;
  const float *g1, *be1, *m1, *v1, *g2, *be2, *m2, *v2;
  unsigned short *A_pc, *W6, *Wq, *Wqa, *Woa, *Wkv, *A6;
  float *peb, *bias6, *s1, *t1, *s2, *t2;
};

__global__ __launch_bounds__(256)
void cast_all(CP p) {
  int c = blockIdx.x * 256 + threadIdx.x;
  const float* src; unsigned short* dst; int row, col, ldd;
  if (c < 2097152) {                       // A_pc: past_cells 16384x1024
    row = c >> 7; col = (c & 127) << 3;
    src = p.pcs + (size_t)row * 1024 + col; dst = p.A_pc; ldd = 1024;
  } else if (c < 3407872) {                // W6: [W_ih|W_hh|W_ac] 4096x2560
    int i = c - 2097152; row = i / 320; col = (i - row * 320) << 3;
    dst = p.W6; ldd = 2560;
    src = (col < 512)  ? p.W_ih + (size_t)row * 512 + col
        : (col < 1536) ? p.W_hh + (size_t)row * 1024 + (col - 512)
                       : p.W_ac + (size_t)row * 1024 + (col - 1536);
  } else if (c < 3604480) {                // Wq: 1024x1536
    int i = c - 3407872; row = i / 192; col = (i - row * 192) << 3;
    src = p.W_q + (size_t)row * 1536 + col; dst = p.Wq; ldd = 1536;
  } else if (c < 3735552) {                // Wqa: 1024x1024
    int i = c - 3604480; row = i >> 7; col = (i & 127) << 3;
    src = p.Wq_a + (size_t)row * 1024 + col; dst = p.Wqa; ldd = 1024;
  } else if (c < 3866624) {                // Woa: 1024x1024
    int i = c - 3735552; row = i >> 7; col = (i & 127) << 3;
    src = p.Wo_a + (size_t)row * 1024 + col; dst = p.Woa; ldd = 1024;
  } else if (c < 4128768) {                // Wkv: 2048x1024 (from 1088-ld)
    int i = c - 3866624; row = i >> 7; col = (i & 127) << 3;
    src = (row < 1024) ? p.Wk_a + (size_t)row * 1088 + col
                       : p.Wv_a + (size_t)(row - 1024) * 1088 + col;
    dst = p.Wkv; ldd = 1024;
  } else if (c < 4227072) {                // A6 cols 0..1536: [x|ph] 512x1536
    int i = c - 4128768; row = i / 192; col = (i - row * 192) << 3;
    src = (col < 512) ? p.x + (size_t)row * 512 + col
                      : p.ph + (size_t)row * 1024 + (col - 512);
    dst = p.A6; ldd = 2560;
  } else if (c < 4292608) {                // peb[w][n]
    int idx = c - 4227072;
    int w = idx >> 11, n = idx & 2047;
    const float* Wrow =
        ((n < 1024) ? (p.Wk_a + (size_t)n * 1088)
                    : (p.Wv_a + (size_t)(n - 1024) * 1088)) + 1024;
    float accv = (n < 1024) ? p.bk[n] : p.bv[n - 1024];
    const float c0 = 0.14391157f;  // ln(10000)/64
#pragma unroll
    for (int j = 0; j < 32; ++j) {
      float ang = (float)w * __expf(-(2.f * j) * c0);
      accv += __sinf(ang) * Wrow[2 * j] + __cosf(ang) * Wrow[2 * j + 1];
    }
    p.peb[idx] = accv;
    return;
  } else {                                 // misc prep
    int i = c - 4292608;
    if (i < 4096) p.bias6[i] = p.b_ih[i] + p.b_ac[i];
    if (i < 1024) {
      float sa = p.g1[i] * rsqrtf(p.v1[i] + 1e-5f);
      p.s1[i] = sa; p.t1[i] = p.be1[i] - p.m1[i] * sa;
      float sp = p.g2[i] * rsqrtf(p.v2[i] + 1e-5f);
      p.s2[i] = sp; p.t2[i] = p.be2[i] - p.m2[i] * sp;
    }
    return;
  }
  f32x4 v0 = *(const f32x4*)src;
  f32x4 v1 = *(const f32x4*)(src + 4);
  u16x8 r;
  r[0] = f2bf(v0.x); r[1] = f2bf(v0.y); r[2] = f2bf(v0.z); r[3] = f2bf(v0.w);
  r[4] = f2bf(v1.x); r[5] = f2bf(v1.y); r[6] = f2bf(v1.z); r[7] = f2bf(v1.w);
  int sc = col ^ ((row & 7) << 3);
  *(u16x8*)(dst + (size_t)row * ldd + sc) = r;
}

// ---------------------------------------------------------------------------
// m97-structure GEMM (unchanged, proven): pre-swizzled bf16 A,B (B^T layout),
// global_load_lds staging, swizzled ds_read_b128 fragments.
// EPI: 0=f32 linear; 1=bf16 swizzled (ld=N); 3=BN + bf16 swizzled into A6@1536
// ---------------------------------------------------------------------------
struct GP2 {
  const unsigned short* A; long lda;
  const unsigned short* B; long ldb;
  const float* bias;
  const float* bnS; const float* bnT;
  float* of; unsigned short* ob;
  int N, K;
};

template<int BM, int BN, int EPI, int ACT>
__global__ __launch_bounds__(256)
void gemm2(GP2 p) {
  __shared__ unsigned short sA[BM * 64];
  __shared__ unsigned short sB[BN * 64];
  const int tid = threadIdx.x, lane = tid & 63, wid = tid >> 6;
  const int col0 = blockIdx.x * BN, row0 = blockIdx.y * BM;
  constexpr int WRS = BM / 2, WCS = BN / 2;
  constexpr int MI = WRS / 16, NI = WCS / 16;
  const int wr = (wid >> 1) * WRS, wc = (wid & 1) * WCS;
  const int g = lane >> 4, lr = lane & 15;
  f32x4 acc[MI][NI] = {};

  for (int kb = 0; kb < p.K; kb += 64) {
    __syncthreads();
#pragma unroll
    for (int ps = 0; ps < (BM * 8) / 256; ++ps) {
      int chunk = ps * 256 + tid;
      int r = chunk >> 3, c8 = chunk & 7;
      gl_lds16(p.A + (size_t)(row0 + r) * p.lda + kb + c8 * 8, &sA[chunk * 8]);
    }
#pragma unroll
    for (int ps = 0; ps < (BN * 8) / 256; ++ps) {
      int chunk = ps * 256 + tid;
      int r = chunk >> 3, c8 = chunk & 7;
      gl_lds16(p.B + (size_t)(col0 + r) * p.ldb + kb + c8 * 8, &sB[chunk * 8]);
    }
    __syncthreads();
#pragma unroll
    for (int kk = 0; kk < 64; kk += 32) {
      s16x8 af[MI], bf_[NI];
#pragma unroll
      for (int i = 0; i < MI; ++i) {
        int ar = wr + i * 16 + lr;
        int sl = ((kk >> 3) + g) ^ (ar & 7);
        af[i] = *(const s16x8*)(&sA[(ar * 8 + sl) * 8]);
      }
#pragma unroll
      for (int i = 0; i < NI; ++i) {
        int br = wc + i * 16 + lr;
        int sl = ((kk >> 3) + g) ^ (br & 7);
        bf_[i] = *(const s16x8*)(&sB[(br * 8 + sl) * 8]);
      }
#pragma unroll
      for (int mi = 0; mi < MI; ++mi)
#pragma unroll
        for (int ni = 0; ni < NI; ++ni)
          acc[mi][ni] = __builtin_amdgcn_mfma_f32_16x16x32_bf16(
              af[mi], bf_[ni], acc[mi][ni], 0, 0, 0);
    }
  }

  // C/D layout (m89): col = lane&15, row = (lane>>4)*4 + reg
#pragma unroll
  for (int mi = 0; mi < MI; ++mi) {
#pragma unroll
    for (int ni = 0; ni < NI; ++ni) {
#pragma unroll
      for (int rg = 0; rg < 4; ++rg) {
        int rr = row0 + wr + mi * 16 + g * 4 + rg;
        int cc = col0 + wc + ni * 16 + lr;
        float v = acc[mi][ni][rg] + p.bias[cc];
        if constexpr (ACT) v = eluf(v);
        if constexpr (EPI == 0) {
          p.of[(size_t)rr * p.N + cc] = v;
        } else if constexpr (EPI == 1) {
          p.ob[(size_t)rr * p.N + (cc ^ ((rr & 7) << 3))] = f2bf(v);
        } else {
          v = v * p.bnS[cc] + p.bnT[cc];
          p.ob[(size_t)rr * 2560 + ((1536 + cc) ^ ((rr & 7) << 3))] = f2bf(v);
        }
      }
    }
  }
}

// ---------------------------------------------------------------------------
// Fused K/V-projection GEMM + attention. Block = (head h, 4 batch rows b0..b0+3).
// M-tile rows r -> (w = r>>2, b = b0 + (r&3)); N-tile cols cc -> K d=cc (cc<64)
// or V d=cc-64. K/V tile -> LDS (aliasing staging buffers), then in-block
// softmax+PV. ctx written bf16 swizzled for G5's A operand.
// ---------------------------------------------------------------------------
__global__ __launch_bounds__(256)
void gkv_attn(const unsigned short* __restrict__ A_pc,
              const unsigned short* __restrict__ Wkv,
              const float* __restrict__ peb,
              const float* __restrict__ Qf,
              unsigned short* __restrict__ ctx) {
  __shared__ unsigned short smem[2 * 128 * 64];  // sA|sB; later kv[128][128]
  __shared__ float prs[4][32];
  __shared__ float qs[4][64];
  unsigned short* sA = smem;
  unsigned short* sB = smem + 128 * 64;

  // XCD-chunked swizzle: 2048 blocks, 8 XCDs -> 16 heads x 16 bgroups per chunk
  int id = blockIdx.x;
  int nid = (id & 7) * 256 + (id >> 3);
  const int h = nid & 15, bg = nid >> 4;
  const int b0 = bg * 4;

  const int tid = threadIdx.x, lane = tid & 63, wid = tid >> 6;
  const int wr = (wid >> 1) * 64, wc = (wid & 1) * 64;
  const int g = lane >> 4, lr = lane & 15;
  f32x4 acc[4][4] = {};

  for (int kb = 0; kb < 1024; kb += 64) {
    __syncthreads();
#pragma unroll
    for (int ps = 0; ps < 4; ++ps) {
      int chunk = ps * 256 + tid;
      int r = chunk >> 3, c8 = chunk & 7;
      int w = r >> 2;
      int srow = w * 512 + b0 + (r & 3);
      int xf = (r & 7) ^ (srow & 7);  // corrective: source swizzled by srow&7
      gl_lds16(A_pc + (size_t)srow * 1024 + kb + ((c8 ^ xf) << 3), &sA[chunk * 8]);
    }
#pragma unroll
    for (int ps = 0; ps < 4; ++ps) {
      int chunk = ps * 256 + tid;
      int r = chunk >> 3, c8 = chunk & 7;
      int n = h * 64 + r + (r >= 64 ? 960 : 0);  // n&7 == r&7 (mod-8 clean)
      gl_lds16(Wkv + (size_t)n * 1024 + kb + (c8 << 3), &sB[chunk * 8]);
    }
    __syncthreads();
#pragma unroll
    for (int kk = 0; kk < 64; kk += 32) {
      s16x8 af[4], bf_[4];
#pragma unroll
      for (int i = 0; i < 4; ++i) {
        int ar = wr + i * 16 + lr;
        int sl = ((kk >> 3) + g) ^ (ar & 7);
        af[i] = *(const s16x8*)(&sA[(ar * 8 + sl) * 8]);
        int br = wc + i * 16 + lr;
        int sl2 = ((kk >> 3) + g) ^ (br & 7);
        bf_[i] = *(const s16x8*)(&sB[(br * 8 + sl2) * 8]);
      }
#pragma unroll
      for (int mi = 0; mi < 4; ++mi)
#pragma unroll
        for (int ni = 0; ni < 4; ++ni)
          acc[mi][ni] = __builtin_amdgcn_mfma_f32_16x16x32_bf16(
              af[mi], bf_[ni], acc[mi][ni], 0, 0, 0);
    }
  }
  __syncthreads();  // all LDS reads done before reuse as kv

  unsigned short (*kv)[128] = (unsigned short(*)[128])smem;
#pragma unroll
  for (int mi = 0; mi < 4; ++mi) {
#pragma unroll
    for (int ni = 0; ni < 4; ++ni) {
#pragma unroll
      for (int rg = 0; rg < 4; ++rg) {
        int rr = wr + mi * 16 + g * 4 + rg;
        int cc = wc + ni * 16 + lr;
        int w = rr >> 2;
        int gcol = h * 64 + cc + (cc >= 64 ? 960 : 0);
        float v = acc[mi][ni][rg] + peb[w * 2048 + gcol];
        v = v > 0.f ? v : __expf(v) - 1.f;
        kv[rr][cc ^ ((rr & 7) << 3)] = f2bf(v);
      }
    }
  }
  qs[wid][lane] = Qf[(size_t)(b0 + wid) * 1024 + h * 64 + lane];
  __syncthreads();

  // attention: wave wv handles b = b0+wv
  const int wv = wid;
  const int w = lane & 31, half = lane >> 5;
  float s = 0.f;
  {
    int r = w * 4 + wv;
    int swz = r & 7;
#pragma unroll
    for (int jj = 0; jj < 4; ++jj) {
      u16x8 kx = *(const u16x8*)(&kv[r][((half * 4 + jj) ^ swz) << 3]);
#pragma unroll
      for (int e = 0; e < 8; ++e)
        s += qs[wv][half * 32 + jj * 8 + e] * bf2f(kx[e]);
    }
  }
  s += __shfl_xor(s, 32);
  s *= 0.125f;  // 1/sqrt(64)
  float mx = s;
#pragma unroll
  for (int off = 16; off; off >>= 1) mx = fmaxf(mx, __shfl_xor(mx, off));
  float e = __expf(s - mx);
  float sum = e;
#pragma unroll
  for (int off = 16; off; off >>= 1) sum += __shfl_xor(sum, off);
  if (lane < 32) prs[wv][lane] = e / sum;

  float c = 0.f;
  const int d = lane;
#pragma unroll 8
  for (int w2 = 0; w2 < 32; ++w2) {
    int r = w2 * 4 + wv;
    c += prs[wv][w2] * bf2f(kv[r][(64 + d) ^ ((r & 7) << 3)]);
  }
  int b = b0 + wv;
  ctx[(size_t)b * 1024 + ((h * 64 + d) ^ ((b & 7) << 3))] = f2bf(c);
}

__global__ __launch_bounds__(256)
void final_k(const float* __restrict__ pre, const float* __restrict__ pcell,
             const float* __restrict__ s2, const float* __restrict__ t2,
             float* __restrict__ out) {
  int i = blockIdx.x * 256 + threadIdx.x;  // [0, 524288)
  int j = i & 1023;
  const float* pm = pre + (size_t)(i >> 10) * 4096;
  float iv = tanhfast(pm[j]);
  float f  = sigf(pm[1024 + j]);
  float ii = sigf(pm[2048 + j]);
  float o  = sigf(pm[3072 + j]);
  float cell = iv * ii + pcell[i] * f;
  float ec = cell > 0.f ? cell : __expf(cell) - 1.f;
  out[i] = (o * ec) * s2[j] + t2[j];
}

extern "C" void kernel_launch(void* const* d_in, const int* in_sizes, int n_in,
                              void* d_out, int out_size, void* d_ws, size_t ws_size,
                              hipStream_t stream) {
  (void)in_sizes; (void)n_in; (void)out_size; (void)ws_size;
  const float* x     = (const float*)d_in[0];
  const float* ph    = (const float*)d_in[1];
  const float* pcell = (const float*)d_in[2];
  const float* pcs   = (const float*)d_in[3];
  const float* W_ih  = (const float*)d_in[4];
  const float* b_ih  = (const float*)d_in[5];
  const float* W_hh  = (const float*)d_in[6];
  const float* W_q   = (const float*)d_in[7];
  const float* b_q   = (const float*)d_in[8];
  const float* W_ac  = (const float*)d_in[9];
  const float* b_ac  = (const float*)d_in[10];
  const float* Wq_a  = (const float*)d_in[11];
  const float* bq_a  = (const float*)d_in[12];
  const float* Wk_a  = (const float*)d_in[13];
  const float* bk_a  = (const float*)d_in[14];
  const float* Wv_a  = (const float*)d_in[15];
  const float* bv_a  = (const float*)d_in[16];
  const float* Wo_a  = (const float*)d_in[17];
  const float* bo_a  = (const float*)d_in[18];

  char* wp = (char*)d_ws;
  auto alloc = [&](size_t bytes) {
    char* r = wp; wp += (bytes + 255) & ~(size_t)255; return r;
  };
  unsigned short* A_pc  = (unsigned short*)alloc((size_t)16384 * 1024 * 2);
  unsigned short* W6    = (unsigned short*)alloc((size_t)4096 * 2560 * 2);
  unsigned short* Wq    = (unsigned short*)alloc((size_t)1024 * 1536 * 2);
  unsigned short* Wqa   = (unsigned short*)alloc((size_t)1024 * 1024 * 2);
  unsigned short* Woa   = (unsigned short*)alloc((size_t)1024 * 1024 * 2);
  unsigned short* Wkv   = (unsigned short*)alloc((size_t)2048 * 1024 * 2);
  unsigned short* A6    = (unsigned short*)alloc((size_t)512 * 2560 * 2);
  unsigned short* q_bf  = (unsigned short*)alloc((size_t)512 * 1024 * 2);
  float*          Qf    = (float*)alloc((size_t)512 * 1024 * 4);
  unsigned short* ctxbf = (unsigned short*)alloc((size_t)512 * 1024 * 2);
  float*          pre   = (float*)alloc((size_t)512 * 4096 * 4);
  float*          peb   = (float*)alloc((size_t)32 * 2048 * 4);
  float*          bias6 = (float*)alloc((size_t)4096 * 4);
  float*          s1    = (float*)alloc((size_t)1024 * 4);
  float*          t1    = (float*)alloc((size_t)1024 * 4);
  float*          s2    = (float*)alloc((size_t)1024 * 4);
  float*          t2    = (float*)alloc((size_t)1024 * 4);

  {
    CP cp = {};
    cp.pcs = pcs; cp.W_ih = W_ih; cp.W_hh = W_hh; cp.W_ac = W_ac; cp.W_q = W_q;
    cp.Wq_a = Wq_a; cp.Wo_a = Wo_a; cp.Wk_a = Wk_a; cp.Wv_a = Wv_a;
    cp.x = x; cp.ph = ph;
    cp.b_ih = b_ih; cp.b_ac = b_ac; cp.bk = bk_a; cp.bv = bv_a;
    cp.g1 = (const float*)d_in[19]; cp.be1 = (const float*)d_in[20];
    cp.m1 = (const float*)d_in[21]; cp.v1 = (const float*)d_in[22];
    cp.g2 = (const float*)d_in[23]; cp.be2 = (const float*)d_in[24];
    cp.m2 = (const float*)d_in[25]; cp.v2 = (const float*)d_in[26];
    cp.A_pc = A_pc; cp.W6 = W6; cp.Wq = Wq; cp.Wqa = Wqa; cp.Woa = Woa;
    cp.Wkv = Wkv; cp.A6 = A6;
    cp.peb = peb; cp.bias6 = bias6; cp.s1 = s1; cp.t1 = t1; cp.s2 = s2; cp.t2 = t2;
    cast_all<<<16784, 256, 0, stream>>>(cp);
  }

  // G1: q = elu([x|ph] @ W_q^T + b_q) -> q_bf (swizzled)
  {
    GP2 p = {};
    p.A = A6; p.lda = 2560; p.B = Wq; p.ldb = 1536;
    p.bias = b_q; p.ob = q_bf; p.N = 1024; p.K = 1536;
    gemm2<64, 64, 1, 1><<<dim3(16, 8), 256, 0, stream>>>(p);
  }
  // G2: Q = q @ Wq_a^T + bq_a -> Qf (f32 linear)
  {
    GP2 p = {};
    p.A = q_bf; p.lda = 1024; p.B = Wqa; p.ldb = 1024;
    p.bias = bq_a; p.of = Qf; p.N = 1024; p.K = 1024;
    gemm2<64, 64, 0, 0><<<dim3(16, 8), 256, 0, stream>>>(p);
  }
  // fused K/V GEMM + attention -> ctxbf (swizzled)
  gkv_attn<<<2048, 256, 0, stream>>>(A_pc, Wkv, peb, Qf, ctxbf);
  // G5: attn = bn(elu(ctx @ Wo_a^T + bo_a)) -> A6 cols 1536.. (bf16 swizzled)
  {
    GP2 p = {};
    p.A = ctxbf; p.lda = 1024; p.B = Woa; p.ldb = 1024;
    p.bias = bo_a; p.bnS = s1; p.bnT = t1; p.ob = A6; p.N = 1024; p.K = 1024;
    gemm2<64, 64, 3, 1><<<dim3(16, 8), 256, 0, stream>>>(p);
  }
  // G6: pre = [x|ph|attn] @ [W_ih|W_hh|W_ac]^T + bias6 -> pre (f32)
  {
    GP2 p = {};
    p.A = A6; p.lda = 2560; p.B = W6; p.ldb = 2560;
    p.bias = bias6; p.of = pre; p.N = 4096; p.K = 2560;
    gemm2<64, 128, 0, 0><<<dim3(32, 8), 256, 0, stream>>>(p);
  }
  final_k<<<2048, 256, 0, stream>>>(pre, pcell, s2, t2, (float*)d_out);
}

// Round 4
// 375.509 us; speedup vs baseline: 1.9722x; 1.0150x over previous
//
#include <hip/hip_runtime.h>
#include <hip/hip_bf16.h>

typedef __attribute__((ext_vector_type(8))) short s16x8;
typedef __attribute__((ext_vector_type(8))) unsigned short u16x8;
typedef __attribute__((ext_vector_type(4))) float f32x4;

__device__ __forceinline__ float bf2f(unsigned short u) {
  union { unsigned int i; float f; } v; v.i = ((unsigned int)u) << 16; return v.f;
}
__device__ __forceinline__ unsigned short f2bf(float f) {
  union { float f; unsigned int i; } v; v.f = f;
  unsigned int u = v.i;
  unsigned int r = (u + 0x7fffu + ((u >> 16) & 1u)) >> 16;
  return (unsigned short)r;
}
__device__ __forceinline__ float eluf(float x) { return x > 0.f ? x : __expf(x) - 1.f; }
__device__ __forceinline__ float sigf(float x) { return 1.f / (1.f + __expf(-x)); }
__device__ __forceinline__ float tanhfast(float x) {
  float ax = fminf(fabsf(x), 15.f);
  float e2 = __expf(2.f * ax);
  float t = (e2 - 1.f) / (e2 + 1.f);
  return x < 0.f ? -t : t;
}

__device__ __forceinline__ void gl_lds16(const unsigned short* g, unsigned short* l) {
  __builtin_amdgcn_global_load_lds(
      (const __attribute__((address_space(1))) void*)g,
      (__attribute__((address_space(3))) void*)l, 16, 0, 0);
}

template<int N> __device__ __forceinline__ void waitv() {
  if constexpr (N == 0) asm volatile("s_waitcnt vmcnt(0)" ::: "memory");
  else if constexpr (N == 3) asm volatile("s_waitcnt vmcnt(3)" ::: "memory");
  else if constexpr (N == 4) asm volatile("s_waitcnt vmcnt(4)" ::: "memory");
  else if constexpr (N == 6) asm volatile("s_waitcnt vmcnt(6)" ::: "memory");
  else if constexpr (N == 8) asm volatile("s_waitcnt vmcnt(8)" ::: "memory");
}
__device__ __forceinline__ void sbar() {
  __builtin_amdgcn_sched_barrier(0);
  __builtin_amdgcn_s_barrier();
  __builtin_amdgcn_sched_barrier(0);
}

// ---------------------------------------------------------------------------
// cast_all: f32 -> bf16, chunk-XOR-swizzled (stored col = col ^ ((row&7)<<3)).
// W6 rows are GATE-INTERLEAVED: stored row n' = j*4 + gate (n = gate*1024+j).
// ---------------------------------------------------------------------------
struct CP {
  const float *pcs, *W_ih, *W_hh, *W_ac, *W_q, *Wq_a, *Wo_a, *Wk_a, *Wv_a, *x, *ph;
  const float *b_ih, *b_ac, *bk, *bv;
  const float *g1, *be1, *m1, *v1, *g2, *be2, *m2, *v2;
  unsigned short *A_pc, *W6, *Wq, *Wqa, *Woa, *Wkv, *A6;
  float *peb, *bias6, *s1, *t1, *s2, *t2;
};

__global__ __launch_bounds__(256)
void cast_all(CP p) {
  int c = blockIdx.x * 256 + threadIdx.x;
  const float* src; unsigned short* dst; int row, col, ldd;
  if (c < 2097152) {                       // A_pc: past_cells 16384x1024
    row = c >> 7; col = (c & 127) << 3;
    src = p.pcs + (size_t)row * 1024 + col; dst = p.A_pc; ldd = 1024;
  } else if (c < 3407872) {                // W6: gate-interleaved 4096x2560
    int i = c - 2097152; int orow = i / 320; col = (i - orow * 320) << 3;
    dst = p.W6; ldd = 2560;
    src = (col < 512)  ? p.W_ih + (size_t)orow * 512 + col
        : (col < 1536) ? p.W_hh + (size_t)orow * 1024 + (col - 512)
                       : p.W_ac + (size_t)orow * 1024 + (col - 1536);
    row = (orow & 1023) * 4 + (orow >> 10);   // j*4 + gate
  } else if (c < 3604480) {                // Wq: 1024x1536
    int i = c - 3407872; row = i / 192; col = (i - row * 192) << 3;
    src = p.W_q + (size_t)row * 1536 + col; dst = p.Wq; ldd = 1536;
  } else if (c < 3735552) {                // Wqa: 1024x1024
    int i = c - 3604480; row = i >> 7; col = (i & 127) << 3;
    src = p.Wq_a + (size_t)row * 1024 + col; dst = p.Wqa; ldd = 1024;
  } else if (c < 3866624) {                // Woa: 1024x1024
    int i = c - 3735552; row = i >> 7; col = (i & 127) << 3;
    src = p.Wo_a + (size_t)row * 1024 + col; dst = p.Woa; ldd = 1024;
  } else if (c < 4128768) {                // Wkv: 2048x1024 (from 1088-ld)
    int i = c - 3866624; row = i >> 7; col = (i & 127) << 3;
    src = (row < 1024) ? p.Wk_a + (size_t)row * 1088 + col
                       : p.Wv_a + (size_t)(row - 1024) * 1088 + col;
    dst = p.Wkv; ldd = 1024;
  } else if (c < 4227072) {                // A6 cols 0..1536: [x|ph] 512x1536
    int i = c - 4128768; row = i / 192; col = (i - row * 192) << 3;
    src = (col < 512) ? p.x + (size_t)row * 512 + col
                      : p.ph + (size_t)row * 1024 + (col - 512);
    dst = p.A6; ldd = 2560;
  } else if (c < 4292608) {                // peb[w][n]
    int idx = c - 4227072;
    int w = idx >> 11, n = idx & 2047;
    const float* Wrow =
        ((n < 1024) ? (p.Wk_a + (size_t)n * 1088)
                    : (p.Wv_a + (size_t)(n - 1024) * 1088)) + 1024;
    float accv = (n < 1024) ? p.bk[n] : p.bv[n - 1024];
    const float c0 = 0.14391157f;  // ln(10000)/64
#pragma unroll
    for (int j = 0; j < 32; ++j) {
      float ang = (float)w * __expf(-(2.f * j) * c0);
      accv += __sinf(ang) * Wrow[2 * j] + __cosf(ang) * Wrow[2 * j + 1];
    }
    p.peb[idx] = accv;
    return;
  } else {                                 // misc prep
    int i = c - 4292608;
    if (i < 4096) p.bias6[(i & 1023) * 4 + (i >> 10)] = p.b_ih[i] + p.b_ac[i];
    if (i < 1024) {
      float sa = p.g1[i] * rsqrtf(p.v1[i] + 1e-5f);
      p.s1[i] = sa; p.t1[i] = p.be1[i] - p.m1[i] * sa;
      float sp = p.g2[i] * rsqrtf(p.v2[i] + 1e-5f);
      p.s2[i] = sp; p.t2[i] = p.be2[i] - p.m2[i] * sp;
    }
    return;
  }
  f32x4 v0 = *(const f32x4*)src;
  f32x4 v1 = *(const f32x4*)(src + 4);
  u16x8 r;
  r[0] = f2bf(v0.x); r[1] = f2bf(v0.y); r[2] = f2bf(v0.z); r[3] = f2bf(v0.w);
  r[4] = f2bf(v1.x); r[5] = f2bf(v1.y); r[6] = f2bf(v1.z); r[7] = f2bf(v1.w);
  int sc = col ^ ((row & 7) << 3);
  *(u16x8*)(dst + (size_t)row * ldd + sc) = r;
}

// ---------------------------------------------------------------------------
// sgemm: latency-optimized small GEMM. 3-buffer distance-2 counted-vmcnt
// pipeline (T4). Pre-swizzled bf16 A,B; gl_lds staging; swizzled ds_read_b128.
// EPI: 0=f32 linear; 1=bf16 swizzled(ld=N); 3=BN+bf16 swizzled into A6@1536;
//      4=fused LSTM-gate final (gate-interleaved cols), writes hidden f32.
// ---------------------------------------------------------------------------
struct GP2 {
  const unsigned short* A; long lda;
  const unsigned short* B; long ldb;
  const float* bias;
  const float* bnS; const float* bnT;   // EPI3: BN scale/shift; EPI4: s2/t2
  const float* pcell;                   // EPI4
  float* of; unsigned short* ob;
  int N, K;
};

template<int BM, int BN, int EPI, int ACT>
__global__ __launch_bounds__(256)
void sgemm(GP2 p) {
  constexpr int LA = (BM * 8) / 256, LB = (BN * 8) / 256, L = LA + LB;
  __shared__ unsigned short sA[3][BM * 64];
  __shared__ unsigned short sB[3][BN * 64];
  const int tid = threadIdx.x, lane = tid & 63, wid = tid >> 6;
  const int col0 = blockIdx.x * BN, row0 = blockIdx.y * BM;
  constexpr int WRS = BM / 2, WCS = BN / 2;
  constexpr int MI = WRS / 16, NI = WCS / 16;
  const int wr = (wid >> 1) * WRS, wc = (wid & 1) * WCS;
  const int g = lane >> 4, lr = lane & 15;
  f32x4 acc[MI][NI] = {};

  auto stage = [&](int buf, int kb) {
#pragma unroll
    for (int i = 0; i < LA; ++i) {
      int chunk = i * 256 + tid;
      int r = chunk >> 3, c8 = chunk & 7;
      gl_lds16(p.A + (size_t)(row0 + r) * p.lda + kb + c8 * 8, &sA[buf][chunk * 8]);
    }
#pragma unroll
    for (int i = 0; i < LB; ++i) {
      int chunk = i * 256 + tid;
      int r = chunk >> 3, c8 = chunk & 7;
      gl_lds16(p.B + (size_t)(col0 + r) * p.ldb + kb + c8 * 8, &sB[buf][chunk * 8]);
    }
  };
  auto compute = [&](int buf) {
#pragma unroll
    for (int kk = 0; kk < 64; kk += 32) {
      s16x8 af[MI], bf_[NI];
#pragma unroll
      for (int i = 0; i < MI; ++i) {
        int ar = wr + i * 16 + lr;
        int sl = ((kk >> 3) + g) ^ (ar & 7);
        af[i] = *(const s16x8*)(&sA[buf][(ar * 8 + sl) * 8]);
      }
#pragma unroll
      for (int i = 0; i < NI; ++i) {
        int br = wc + i * 16 + lr;
        int sl = ((kk >> 3) + g) ^ (br & 7);
        bf_[i] = *(const s16x8*)(&sB[buf][(br * 8 + sl) * 8]);
      }
#pragma unroll
      for (int mi = 0; mi < MI; ++mi)
#pragma unroll
        for (int ni = 0; ni < NI; ++ni)
          acc[mi][ni] = __builtin_amdgcn_mfma_f32_16x16x32_bf16(
              af[mi], bf_[ni], acc[mi][ni], 0, 0, 0);
    }
  };

  const int nt = p.K >> 6;
  stage(0, 0);
  stage(1, 64);
  int bufc = 0;
  for (int t = 0; t < nt; ++t) {
    if (t + 2 < nt) {
      stage(bufc >= 1 ? bufc - 1 : bufc + 2, (t + 2) << 6);
      waitv<2 * L>();
    } else if (t + 1 < nt) {
      waitv<L>();
    } else {
      waitv<0>();
    }
    sbar();
    compute(bufc);
    sbar();
    bufc = bufc < 2 ? bufc + 1 : 0;
  }

  // C/D layout (m89): col = lane&15, row = (lane>>4)*4 + reg
#pragma unroll
  for (int mi = 0; mi < MI; ++mi) {
#pragma unroll
    for (int ni = 0; ni < NI; ++ni) {
#pragma unroll
      for (int rg = 0; rg < 4; ++rg) {
        int rr = row0 + wr + mi * 16 + g * 4 + rg;
        int cc = col0 + wc + ni * 16 + lr;
        float v = acc[mi][ni][rg] + p.bias[cc];
        if constexpr (ACT) v = eluf(v);
        if constexpr (EPI == 0) {
          p.of[(size_t)rr * p.N + cc] = v;
        } else if constexpr (EPI == 1) {
          p.ob[(size_t)rr * p.N + (cc ^ ((rr & 7) << 3))] = f2bf(v);
        } else if constexpr (EPI == 3) {
          v = v * p.bnS[cc] + p.bnT[cc];
          p.ob[(size_t)rr * 2560 + ((1536 + cc) ^ ((rr & 7) << 3))] = f2bf(v);
        } else {
          // EPI 4: cc = j*4 + gate. Lanes base..base+3 hold gates 0..3 of j.
          int base = lane & ~3;
          float g0 = __shfl(v, base);
          float g1 = __shfl(v, base | 1);
          float g2v = __shfl(v, base | 2);
          float g3 = __shfl(v, base | 3);
          if ((lane & 3) == 0) {
            int j = cc >> 2;
            float iv = tanhfast(g0);
            float fg = sigf(g1);
            float ig = sigf(g2v);
            float og = sigf(g3);
            float cell = iv * ig + p.pcell[(size_t)rr * 1024 + j] * fg;
            float ec = cell > 0.f ? cell : __expf(cell) - 1.f;
            p.of[(size_t)rr * 1024 + j] = (og * ec) * p.bnS[j] + p.bnT[j];
          }
        }
      }
    }
  }
}

// ---------------------------------------------------------------------------
// Fused K/V-projection GEMM + attention (m97-style loop, proven round 2).
// ---------------------------------------------------------------------------
__global__ __launch_bounds__(256)
void gkv_attn(const unsigned short* __restrict__ A_pc,
              const unsigned short* __restrict__ Wkv,
              const float* __restrict__ peb,
              const float* __restrict__ Qf,
              unsigned short* __restrict__ ctx) {
  __shared__ unsigned short smem[2 * 128 * 64];  // sA|sB; later kv[128][128]
  __shared__ float prs[4][32];
  __shared__ float qs[4][64];
  unsigned short* sA = smem;
  unsigned short* sB = smem + 128 * 64;

  int id = blockIdx.x;
  int nid = (id & 7) * 256 + (id >> 3);
  const int h = nid & 15, bg = nid >> 4;
  const int b0 = bg * 4;

  const int tid = threadIdx.x, lane = tid & 63, wid = tid >> 6;
  const int wr = (wid >> 1) * 64, wc = (wid & 1) * 64;
  const int g = lane >> 4, lr = lane & 15;
  f32x4 acc[4][4] = {};

  for (int kb = 0; kb < 1024; kb += 64) {
    __syncthreads();
#pragma unroll
    for (int ps = 0; ps < 4; ++ps) {
      int chunk = ps * 256 + tid;
      int r = chunk >> 3, c8 = chunk & 7;
      int w = r >> 2;
      int srow = w * 512 + b0 + (r & 3);
      int xf = (r & 7) ^ (srow & 7);
      gl_lds16(A_pc + (size_t)srow * 1024 + kb + ((c8 ^ xf) << 3), &sA[chunk * 8]);
    }
#pragma unroll
    for (int ps = 0; ps < 4; ++ps) {
      int chunk = ps * 256 + tid;
      int r = chunk >> 3, c8 = chunk & 7;
      int n = h * 64 + r + (r >= 64 ? 960 : 0);
      gl_lds16(Wkv + (size_t)n * 1024 + kb + (c8 << 3), &sB[chunk * 8]);
    }
    __syncthreads();
#pragma unroll
    for (int kk = 0; kk < 64; kk += 32) {
      s16x8 af[4], bf_[4];
#pragma unroll
      for (int i = 0; i < 4; ++i) {
        int ar = wr + i * 16 + lr;
        int sl = ((kk >> 3) + g) ^ (ar & 7);
        af[i] = *(const s16x8*)(&sA[(ar * 8 + sl) * 8]);
        int br = wc + i * 16 + lr;
        int sl2 = ((kk >> 3) + g) ^ (br & 7);
        bf_[i] = *(const s16x8*)(&sB[(br * 8 + sl2) * 8]);
      }
#pragma unroll
      for (int mi = 0; mi < 4; ++mi)
#pragma unroll
        for (int ni = 0; ni < 4; ++ni)
          acc[mi][ni] = __builtin_amdgcn_mfma_f32_16x16x32_bf16(
              af[mi], bf_[ni], acc[mi][ni], 0, 0, 0);
    }
  }
  __syncthreads();

  unsigned short (*kv)[128] = (unsigned short(*)[128])smem;
#pragma unroll
  for (int mi = 0; mi < 4; ++mi) {
#pragma unroll
    for (int ni = 0; ni < 4; ++ni) {
#pragma unroll
      for (int rg = 0; rg < 4; ++rg) {
        int rr = wr + mi * 16 + g * 4 + rg;
        int cc = wc + ni * 16 + lr;
        int w = rr >> 2;
        int gcol = h * 64 + cc + (cc >= 64 ? 960 : 0);
        float v = acc[mi][ni][rg] + peb[w * 2048 + gcol];
        v = v > 0.f ? v : __expf(v) - 1.f;
        kv[rr][cc ^ ((rr & 7) << 3)] = f2bf(v);
      }
    }
  }
  qs[wid][lane] = Qf[(size_t)(b0 + wid) * 1024 + h * 64 + lane];
  __syncthreads();

  const int wv = wid;
  const int w = lane & 31, half = lane >> 5;
  float s = 0.f;
  {
    int r = w * 4 + wv;
    int swz = r & 7;
#pragma unroll
    for (int jj = 0; jj < 4; ++jj) {
      u16x8 kx = *(const u16x8*)(&kv[r][((half * 4 + jj) ^ swz) << 3]);
#pragma unroll
      for (int e = 0; e < 8; ++e)
        s += qs[wv][half * 32 + jj * 8 + e] * bf2f(kx[e]);
    }
  }
  s += __shfl_xor(s, 32);
  s *= 0.125f;
  float mx = s;
#pragma unroll
  for (int off = 16; off; off >>= 1) mx = fmaxf(mx, __shfl_xor(mx, off));
  float e = __expf(s - mx);
  float sum = e;
#pragma unroll
  for (int off = 16; off; off >>= 1) sum += __shfl_xor(sum, off);
  if (lane < 32) prs[wv][lane] = e / sum;

  float c = 0.f;
  const int d = lane;
#pragma unroll 8
  for (int w2 = 0; w2 < 32; ++w2) {
    int r = w2 * 4 + wv;
    c += prs[wv][w2] * bf2f(kv[r][(64 + d) ^ ((r & 7) << 3)]);
  }
  int b = b0 + wv;
  ctx[(size_t)b * 1024 + ((h * 64 + d) ^ ((b & 7) << 3))] = f2bf(c);
}

extern "C" void kernel_launch(void* const* d_in, const int* in_sizes, int n_in,
                              void* d_out, int out_size, void* d_ws, size_t ws_size,
                              hipStream_t stream) {
  (void)in_sizes; (void)n_in; (void)out_size; (void)ws_size;
  const float* x     = (const float*)d_in[0];
  const float* ph    = (const float*)d_in[1];
  const float* pcell = (const float*)d_in[2];
  const float* pcs   = (const float*)d_in[3];
  const float* W_ih  = (const float*)d_in[4];
  const float* b_ih  = (const float*)d_in[5];
  const float* W_hh  = (const float*)d_in[6];
  const float* W_q   = (const float*)d_in[7];
  const float* b_q   = (const float*)d_in[8];
  const float* W_ac  = (const float*)d_in[9];
  const float* b_ac  = (const float*)d_in[10];
  const float* Wq_a  = (const float*)d_in[11];
  const float* bq_a  = (const float*)d_in[12];
  const float* Wk_a  = (const float*)d_in[13];
  const float* bk_a  = (const float*)d_in[14];
  const float* Wv_a  = (const float*)d_in[15];
  const float* bv_a  = (const float*)d_in[16];
  const float* Wo_a  = (const float*)d_in[17];
  const float* bo_a  = (const float*)d_in[18];

  char* wp = (char*)d_ws;
  auto alloc = [&](size_t bytes) {
    char* r = wp; wp += (bytes + 255) & ~(size_t)255; return r;
  };
  unsigned short* A_pc  = (unsigned short*)alloc((size_t)16384 * 1024 * 2);
  unsigned short* W6    = (unsigned short*)alloc((size_t)4096 * 2560 * 2);
  unsigned short* Wq    = (unsigned short*)alloc((size_t)1024 * 1536 * 2);
  unsigned short* Wqa   = (unsigned short*)alloc((size_t)1024 * 1024 * 2);
  unsigned short* Woa   = (unsigned short*)alloc((size_t)1024 * 1024 * 2);
  unsigned short* Wkv   = (unsigned short*)alloc((size_t)2048 * 1024 * 2);
  unsigned short* A6    = (unsigned short*)alloc((size_t)512 * 2560 * 2);
  unsigned short* q_bf  = (unsigned short*)alloc((size_t)512 * 1024 * 2);
  float*          Qf    = (float*)alloc((size_t)512 * 1024 * 4);
  unsigned short* ctxbf = (unsigned short*)alloc((size_t)512 * 1024 * 2);
  float*          peb   = (float*)alloc((size_t)32 * 2048 * 4);
  float*          bias6 = (float*)alloc((size_t)4096 * 4);
  float*          s1    = (float*)alloc((size_t)1024 * 4);
  float*          t1    = (float*)alloc((size_t)1024 * 4);
  float*          s2    = (float*)alloc((size_t)1024 * 4);
  float*          t2    = (float*)alloc((size_t)1024 * 4);

  {
    CP cp = {};
    cp.pcs = pcs; cp.W_ih = W_ih; cp.W_hh = W_hh; cp.W_ac = W_ac; cp.W_q = W_q;
    cp.Wq_a = Wq_a; cp.Wo_a = Wo_a; cp.Wk_a = Wk_a; cp.Wv_a = Wv_a;
    cp.x = x; cp.ph = ph;
    cp.b_ih = b_ih; cp.b_ac = b_ac; cp.bk = bk_a; cp.bv = bv_a;
    cp.g1 = (const float*)d_in[19]; cp.be1 = (const float*)d_in[20];
    cp.m1 = (const float*)d_in[21]; cp.v1 = (const float*)d_in[22];
    cp.g2 = (const float*)d_in[23]; cp.be2 = (const float*)d_in[24];
    cp.m2 = (const float*)d_in[25]; cp.v2 = (const float*)d_in[26];
    cp.A_pc = A_pc; cp.W6 = W6; cp.Wq = Wq; cp.Wqa = Wqa; cp.Woa = Woa;
    cp.Wkv = Wkv; cp.A6 = A6;
    cp.peb = peb; cp.bias6 = bias6; cp.s1 = s1; cp.t1 = t1; cp.s2 = s2; cp.t2 = t2;
    cast_all<<<16784, 256, 0, stream>>>(cp);
  }

  // G1: q = elu([x|ph] @ W_q^T + b_q) -> q_bf (swizzled)
  {
    GP2 p = {};
    p.A = A6; p.lda = 2560; p.B = Wq; p.ldb = 1536;
    p.bias = b_q; p.ob = q_bf; p.N = 1024; p.K = 1536;
    sgemm<32, 64, 1, 1><<<dim3(16, 16), 256, 0, stream>>>(p);
  }
  // G2: Q = q @ Wq_a^T + bq_a -> Qf (f32 linear)
  {
    GP2 p = {};
    p.A = q_bf; p.lda = 1024; p.B = Wqa; p.ldb = 1024;
    p.bias = bq_a; p.of = Qf; p.N = 1024; p.K = 1024;
    sgemm<32, 64, 0, 0><<<dim3(16, 16), 256, 0, stream>>>(p);
  }
  // fused K/V GEMM + attention -> ctxbf (swizzled)
  gkv_attn<<<2048, 256, 0, stream>>>(A_pc, Wkv, peb, Qf, ctxbf);
  // G5: attn = bn(elu(ctx @ Wo_a^T + bo_a)) -> A6 cols 1536.. (bf16 swizzled)
  {
    GP2 p = {};
    p.A = ctxbf; p.lda = 1024; p.B = Woa; p.ldb = 1024;
    p.bias = bo_a; p.bnS = s1; p.bnT = t1; p.ob = A6; p.N = 1024; p.K = 1024;
    sgemm<32, 64, 3, 1><<<dim3(16, 16), 256, 0, stream>>>(p);
  }
  // G6 + fused final: hidden -> d_out (f32). Gate-interleaved W6/bias6.
  {
    GP2 p = {};
    p.A = A6; p.lda = 2560; p.B = W6; p.ldb = 2560;
    p.bias = bias6; p.bnS = s2; p.bnT = t2; p.pcell = pcell;
    p.of = (float*)d_out; p.N = 4096; p.K = 2560;
    sgemm<64, 64, 4, 0><<<dim3(64, 8), 256, 0, stream>>>(p);
  }
}

// Round 5
// 351.386 us; speedup vs baseline: 2.1076x; 1.0687x over previous
//
#include <hip/hip_runtime.h>
#include <hip/hip_bf16.h>

typedef __attribute__((ext_vector_type(8))) short s16x8;
typedef __attribute__((ext_vector_type(8))) unsigned short u16x8;
typedef __attribute__((ext_vector_type(4))) float f32x4;

__device__ __forceinline__ float bf2f(unsigned short u) {
  union { unsigned int i; float f; } v; v.i = ((unsigned int)u) << 16; return v.f;
}
__device__ __forceinline__ unsigned short f2bf(float f) {
  union { float f; unsigned int i; } v; v.f = f;
  unsigned int u = v.i;
  unsigned int r = (u + 0x7fffu + ((u >> 16) & 1u)) >> 16;
  return (unsigned short)r;
}
__device__ __forceinline__ float eluf(float x) { return x > 0.f ? x : __expf(x) - 1.f; }
__device__ __forceinline__ float sigf(float x) { return 1.f / (1.f + __expf(-x)); }
__device__ __forceinline__ float tanhfast(float x) {
  float ax = fminf(fabsf(x), 15.f);
  float e2 = __expf(2.f * ax);
  float t = (e2 - 1.f) / (e2 + 1.f);
  return x < 0.f ? -t : t;
}

__device__ __forceinline__ void gl_lds16(const unsigned short* g, unsigned short* l) {
  __builtin_amdgcn_global_load_lds(
      (const __attribute__((address_space(1))) void*)g,
      (__attribute__((address_space(3))) void*)l, 16, 0, 0);
}

template<int N> __device__ __forceinline__ void waitv() {
  if constexpr (N == 0) asm volatile("s_waitcnt vmcnt(0)" ::: "memory");
  else if constexpr (N == 3) asm volatile("s_waitcnt vmcnt(3)" ::: "memory");
  else if constexpr (N == 4) asm volatile("s_waitcnt vmcnt(4)" ::: "memory");
  else if constexpr (N == 6) asm volatile("s_waitcnt vmcnt(6)" ::: "memory");
  else if constexpr (N == 8) asm volatile("s_waitcnt vmcnt(8)" ::: "memory");
}
__device__ __forceinline__ void sbar() {
  __builtin_amdgcn_sched_barrier(0);
  __builtin_amdgcn_s_barrier();
  __builtin_amdgcn_sched_barrier(0);
}

// ---------------------------------------------------------------------------
// cast_all: f32 -> bf16, chunk-XOR-swizzled (stored col = col ^ ((row&7)<<3)).
// W6 rows are GATE-INTERLEAVED: stored row n' = j*4 + gate (n = gate*1024+j).
// ---------------------------------------------------------------------------
struct CP {
  const float *pcs, *W_ih, *W_hh, *W_ac, *W_q, *Wq_a, *Wo_a, *Wk_a, *Wv_a, *x, *ph;
  const float *b_ih, *b_ac, *bk, *bv;
  const float *g1, *be1, *m1, *v1, *g2, *be2, *m2, *v2;
  unsigned short *A_pc, *W6, *Wq, *Wqa, *Woa, *Wkv, *A6;
  float *peb, *bias6, *s1, *t1, *s2, *t2;
};

__global__ __launch_bounds__(256)
void cast_all(CP p) {
  int c = blockIdx.x * 256 + threadIdx.x;
  const float* src; unsigned short* dst; int row, col, ldd;
  if (c < 2097152) {                       // A_pc: past_cells 16384x1024
    row = c >> 7; col = (c & 127) << 3;
    src = p.pcs + (size_t)row * 1024 + col; dst = p.A_pc; ldd = 1024;
  } else if (c < 3407872) {                // W6: gate-interleaved 4096x2560
    int i = c - 2097152; int orow = i / 320; col = (i - orow * 320) << 3;
    dst = p.W6; ldd = 2560;
    src = (col < 512)  ? p.W_ih + (size_t)orow * 512 + col
        : (col < 1536) ? p.W_hh + (size_t)orow * 1024 + (col - 512)
                       : p.W_ac + (size_t)orow * 1024 + (col - 1536);
    row = (orow & 1023) * 4 + (orow >> 10);   // j*4 + gate
  } else if (c < 3604480) {                // Wq: 1024x1536
    int i = c - 3407872; row = i / 192; col = (i - row * 192) << 3;
    src = p.W_q + (size_t)row * 1536 + col; dst = p.Wq; ldd = 1536;
  } else if (c < 3735552) {                // Wqa: 1024x1024
    int i = c - 3604480; row = i >> 7; col = (i & 127) << 3;
    src = p.Wq_a + (size_t)row * 1024 + col; dst = p.Wqa; ldd = 1024;
  } else if (c < 3866624) {                // Woa: 1024x1024
    int i = c - 3735552; row = i >> 7; col = (i & 127) << 3;
    src = p.Wo_a + (size_t)row * 1024 + col; dst = p.Woa; ldd = 1024;
  } else if (c < 4128768) {                // Wkv: 2048x1024 (from 1088-ld)
    int i = c - 3866624; row = i >> 7; col = (i & 127) << 3;
    src = (row < 1024) ? p.Wk_a + (size_t)row * 1088 + col
                       : p.Wv_a + (size_t)(row - 1024) * 1088 + col;
    dst = p.Wkv; ldd = 1024;
  } else if (c < 4227072) {                // A6 cols 0..1536: [x|ph] 512x1536
    int i = c - 4128768; row = i / 192; col = (i - row * 192) << 3;
    src = (col < 512) ? p.x + (size_t)row * 512 + col
                      : p.ph + (size_t)row * 1024 + (col - 512);
    dst = p.A6; ldd = 2560;
  } else if (c < 4292608) {                // peb[w][n]
    int idx = c - 4227072;
    int w = idx >> 11, n = idx & 2047;
    const float* Wrow =
        ((n < 1024) ? (p.Wk_a + (size_t)n * 1088)
                    : (p.Wv_a + (size_t)(n - 1024) * 1088)) + 1024;
    float accv = (n < 1024) ? p.bk[n] : p.bv[n - 1024];
    const float c0 = 0.14391157f;  // ln(10000)/64
#pragma unroll
    for (int j = 0; j < 32; ++j) {
      float ang = (float)w * __expf(-(2.f * j) * c0);
      accv += __sinf(ang) * Wrow[2 * j] + __cosf(ang) * Wrow[2 * j + 1];
    }
    p.peb[idx] = accv;
    return;
  } else {                                 // misc prep
    int i = c - 4292608;
    if (i < 4096) p.bias6[(i & 1023) * 4 + (i >> 10)] = p.b_ih[i] + p.b_ac[i];
    if (i < 1024) {
      float sa = p.g1[i] * rsqrtf(p.v1[i] + 1e-5f);
      p.s1[i] = sa; p.t1[i] = p.be1[i] - p.m1[i] * sa;
      float sp = p.g2[i] * rsqrtf(p.v2[i] + 1e-5f);
      p.s2[i] = sp; p.t2[i] = p.be2[i] - p.m2[i] * sp;
    }
    return;
  }
  f32x4 v0 = *(const f32x4*)src;
  f32x4 v1 = *(const f32x4*)(src + 4);
  u16x8 r;
  r[0] = f2bf(v0.x); r[1] = f2bf(v0.y); r[2] = f2bf(v0.z); r[3] = f2bf(v0.w);
  r[4] = f2bf(v1.x); r[5] = f2bf(v1.y); r[6] = f2bf(v1.z); r[7] = f2bf(v1.w);
  int sc = col ^ ((row & 7) << 3);
  *(u16x8*)(dst + (size_t)row * ldd + sc) = r;
}

// ---------------------------------------------------------------------------
// sgemm: latency-optimized small GEMM. 3-buffer distance-2 counted-vmcnt
// pipeline (T4). Pre-swizzled bf16 A,B; gl_lds staging; swizzled ds_read_b128.
// EPI: 0=f32 linear; 1=bf16 swizzled(ld=N); 3=BN+bf16 swizzled into A6@1536;
//      4=fused LSTM-gate final (gate-interleaved cols), writes hidden f32.
// ---------------------------------------------------------------------------
struct GP2 {
  const unsigned short* A; long lda;
  const unsigned short* B; long ldb;
  const float* bias;
  const float* bnS; const float* bnT;   // EPI3: BN scale/shift; EPI4: s2/t2
  const float* pcell;                   // EPI4
  float* of; unsigned short* ob;
  int N, K;
};

template<int BM, int BN, int EPI, int ACT>
__global__ __launch_bounds__(256)
void sgemm(GP2 p) {
  constexpr int LA = (BM * 8) / 256, LB = (BN * 8) / 256, L = LA + LB;
  __shared__ unsigned short sA[3][BM * 64];
  __shared__ unsigned short sB[3][BN * 64];
  const int tid = threadIdx.x, lane = tid & 63, wid = tid >> 6;
  const int col0 = blockIdx.x * BN, row0 = blockIdx.y * BM;
  constexpr int WRS = BM / 2, WCS = BN / 2;
  constexpr int MI = WRS / 16, NI = WCS / 16;
  const int wr = (wid >> 1) * WRS, wc = (wid & 1) * WCS;
  const int g = lane >> 4, lr = lane & 15;
  f32x4 acc[MI][NI] = {};

  auto stage = [&](int buf, int kb) {
#pragma unroll
    for (int i = 0; i < LA; ++i) {
      int chunk = i * 256 + tid;
      int r = chunk >> 3, c8 = chunk & 7;
      gl_lds16(p.A + (size_t)(row0 + r) * p.lda + kb + c8 * 8, &sA[buf][chunk * 8]);
    }
#pragma unroll
    for (int i = 0; i < LB; ++i) {
      int chunk = i * 256 + tid;
      int r = chunk >> 3, c8 = chunk & 7;
      gl_lds16(p.B + (size_t)(col0 + r) * p.ldb + kb + c8 * 8, &sB[buf][chunk * 8]);
    }
  };
  auto compute = [&](int buf) {
#pragma unroll
    for (int kk = 0; kk < 64; kk += 32) {
      s16x8 af[MI], bf_[NI];
#pragma unroll
      for (int i = 0; i < MI; ++i) {
        int ar = wr + i * 16 + lr;
        int sl = ((kk >> 3) + g) ^ (ar & 7);
        af[i] = *(const s16x8*)(&sA[buf][(ar * 8 + sl) * 8]);
      }
#pragma unroll
      for (int i = 0; i < NI; ++i) {
        int br = wc + i * 16 + lr;
        int sl = ((kk >> 3) + g) ^ (br & 7);
        bf_[i] = *(const s16x8*)(&sB[buf][(br * 8 + sl) * 8]);
      }
#pragma unroll
      for (int mi = 0; mi < MI; ++mi)
#pragma unroll
        for (int ni = 0; ni < NI; ++ni)
          acc[mi][ni] = __builtin_amdgcn_mfma_f32_16x16x32_bf16(
              af[mi], bf_[ni], acc[mi][ni], 0, 0, 0);
    }
  };

  const int nt = p.K >> 6;
  stage(0, 0);
  stage(1, 64);
  int bufc = 0;
  for (int t = 0; t < nt; ++t) {
    if (t + 2 < nt) {
      stage(bufc >= 1 ? bufc - 1 : bufc + 2, (t + 2) << 6);
      waitv<2 * L>();
    } else if (t + 1 < nt) {
      waitv<L>();
    } else {
      waitv<0>();
    }
    sbar();
    compute(bufc);
    sbar();
    bufc = bufc < 2 ? bufc + 1 : 0;
  }

  // C/D layout (m89): col = lane&15, row = (lane>>4)*4 + reg
#pragma unroll
  for (int mi = 0; mi < MI; ++mi) {
#pragma unroll
    for (int ni = 0; ni < NI; ++ni) {
#pragma unroll
      for (int rg = 0; rg < 4; ++rg) {
        int rr = row0 + wr + mi * 16 + g * 4 + rg;
        int cc = col0 + wc + ni * 16 + lr;
        float v = acc[mi][ni][rg] + p.bias[cc];
        if constexpr (ACT) v = eluf(v);
        if constexpr (EPI == 0) {
          p.of[(size_t)rr * p.N + cc] = v;
        } else if constexpr (EPI == 1) {
          p.ob[(size_t)rr * p.N + (cc ^ ((rr & 7) << 3))] = f2bf(v);
        } else if constexpr (EPI == 3) {
          v = v * p.bnS[cc] + p.bnT[cc];
          p.ob[(size_t)rr * 2560 + ((1536 + cc) ^ ((rr & 7) << 3))] = f2bf(v);
        } else {
          // EPI 4: cc = j*4 + gate. Lanes base..base+3 hold gates 0..3 of j.
          int base = lane & ~3;
          float g0 = __shfl(v, base);
          float g1 = __shfl(v, base | 1);
          float g2v = __shfl(v, base | 2);
          float g3 = __shfl(v, base | 3);
          if ((lane & 3) == 0) {
            int j = cc >> 2;
            float iv = tanhfast(g0);
            float fg = sigf(g1);
            float ig = sigf(g2v);
            float og = sigf(g3);
            float cell = iv * ig + p.pcell[(size_t)rr * 1024 + j] * fg;
            float ec = cell > 0.f ? cell : __expf(cell) - 1.f;
            p.of[(size_t)rr * 1024 + j] = (og * ec) * p.bnS[j] + p.bnT[j];
          }
        }
      }
    }
  }
}

// ---------------------------------------------------------------------------
// Fused K/V-projection GEMM + attention, WIDE tile: 128 rows (32 w x 4 b) x
// 256 cols (2 heads x [64 K | 64 V]). 2-phase proven loop; A staged once per
// 2 heads; 64 MFMA per k-step per wave.
// ---------------------------------------------------------------------------
__global__ __launch_bounds__(256, 2)
void gkv_attn(const unsigned short* __restrict__ A_pc,
              const unsigned short* __restrict__ Wkv,
              const float* __restrict__ peb,
              const float* __restrict__ Qf,
              unsigned short* __restrict__ ctx) {
  __shared__ unsigned short smem[128 * 256];   // staging 48KB; later kv 64KB
  __shared__ float prs[8][32];
  __shared__ float qs[4][128];
  unsigned short* sA = smem;                   // 128x64
  unsigned short* sB = smem + 128 * 64;        // 256x64

  // XCD-chunked swizzle: 1024 blocks = 8 xcd-chunks x 128. Same-bg blocks
  // (sharing the A panel) land on one XCD: bg = nid>>3, hp = nid&7.
  int id = blockIdx.x;
  int nid = (id & 7) * 128 + (id >> 3);
  const int hp = nid & 7, bg = nid >> 3;
  const int h_base = hp * 2;
  const int b0 = bg * 4;

  const int tid = threadIdx.x, lane = tid & 63, wid = tid >> 6;
  const int wr = (wid >> 1) * 64, wc = (wid & 1) * 128;
  const int g = lane >> 4, lr = lane & 15;
  f32x4 acc[4][8] = {};

  for (int kb = 0; kb < 1024; kb += 64) {
    __syncthreads();
#pragma unroll
    for (int ps = 0; ps < 4; ++ps) {           // A: 1024 chunks
      int chunk = ps * 256 + tid;
      int r = chunk >> 3, c8 = chunk & 7;
      int w = r >> 2;
      int srow = w * 512 + b0 + (r & 3);
      int xf = (r & 7) ^ (srow & 7);           // corrective source swizzle
      gl_lds16(A_pc + (size_t)srow * 1024 + kb + ((c8 ^ xf) << 3), &sA[chunk * 8]);
    }
#pragma unroll
    for (int ps = 0; ps < 8; ++ps) {           // B: 2048 chunks
      int chunk = ps * 256 + tid;
      int r = chunk >> 3, c8 = chunk & 7;
      int c7 = r & 127, h2 = r >> 7;
      int n = (h_base + h2) * 64 + (c7 & 63) + ((c7 >> 6) << 10);  // n&7==r&7
      gl_lds16(Wkv + (size_t)n * 1024 + kb + (c8 << 3), &sB[chunk * 8]);
    }
    __syncthreads();
#pragma unroll
    for (int kk = 0; kk < 64; kk += 32) {
      s16x8 af[4], bf_[8];
#pragma unroll
      for (int i = 0; i < 4; ++i) {
        int ar = wr + i * 16 + lr;
        int sl = ((kk >> 3) + g) ^ (ar & 7);
        af[i] = *(const s16x8*)(&sA[(ar * 8 + sl) * 8]);
      }
#pragma unroll
      for (int i = 0; i < 8; ++i) {
        int br = wc + i * 16 + lr;
        int sl2 = ((kk >> 3) + g) ^ (br & 7);
        bf_[i] = *(const s16x8*)(&sB[(br * 8 + sl2) * 8]);
      }
#pragma unroll
      for (int mi = 0; mi < 4; ++mi)
#pragma unroll
        for (int ni = 0; ni < 8; ++ni)
          acc[mi][ni] = __builtin_amdgcn_mfma_f32_16x16x32_bf16(
              af[mi], bf_[ni], acc[mi][ni], 0, 0, 0);
    }
  }
  __syncthreads();  // all LDS reads done before reuse as kv

  unsigned short (*kv)[256] = (unsigned short(*)[256])smem;
#pragma unroll
  for (int mi = 0; mi < 4; ++mi) {
#pragma unroll
    for (int ni = 0; ni < 8; ++ni) {
#pragma unroll
      for (int rg = 0; rg < 4; ++rg) {
        int rr = wr + mi * 16 + g * 4 + rg;     // 0..127 (w = rr>>2, b-idx = rr&3)
        int cc = wc + ni * 16 + lr;             // 0..255
        int w = rr >> 2;
        int c7 = cc & 127, h2 = cc >> 7;
        int gcol = (h_base + h2) * 64 + (c7 & 63) + ((c7 >> 6) << 10);
        float v = acc[mi][ni][rg] + peb[w * 2048 + gcol];
        v = v > 0.f ? v : __expf(v) - 1.f;
        kv[rr][cc ^ ((rr & 7) << 3)] = f2bf(v);
      }
    }
  }
  {
    int i0 = tid;
    qs[i0 >> 7][i0 & 127] =
        Qf[(size_t)(b0 + (i0 >> 7)) * 1024 + h_base * 64 + (i0 & 127)];
    int i1 = tid + 256;
    qs[i1 >> 7][i1 & 127] =
        Qf[(size_t)(b0 + (i1 >> 7)) * 1024 + h_base * 64 + (i1 & 127)];
  }
  __syncthreads();

  // attention: wave wid handles pairs p = wid*2, wid*2+1 (bb = p&3, h2 = p>>2)
  const int w = lane & 31, half = lane >> 5;
#pragma unroll
  for (int pi = 0; pi < 2; ++pi) {
    int p = wid * 2 + pi;
    int bb = p & 3, h2 = p >> 2;
    int r = w * 4 + bb;
    int swz = r & 7;
    float s = 0.f;
#pragma unroll
    for (int jj = 0; jj < 4; ++jj) {
      int c8idx = h2 * 16 + half * 4 + jj;
      u16x8 kx = *(const u16x8*)(&kv[r][(c8idx ^ swz) << 3]);
#pragma unroll
      for (int e = 0; e < 8; ++e)
        s += qs[bb][h2 * 64 + half * 32 + jj * 8 + e] * bf2f(kx[e]);
    }
    s += __shfl_xor(s, 32);
    s *= 0.125f;  // 1/sqrt(64)
    float mx = s;
#pragma unroll
    for (int off = 16; off; off >>= 1) mx = fmaxf(mx, __shfl_xor(mx, off));
    float e = __expf(s - mx);
    float sum = e;
#pragma unroll
    for (int off = 16; off; off >>= 1) sum += __shfl_xor(sum, off);
    if (lane < 32) prs[p][lane] = e / sum;
    __builtin_amdgcn_wave_barrier();

    float c = 0.f;
    const int d = lane;
    int vcol = h2 * 128 + 64 + d;
#pragma unroll 8
    for (int w2 = 0; w2 < 32; ++w2) {
      int r2 = w2 * 4 + bb;
      c += prs[p][w2] * bf2f(kv[r2][vcol ^ ((r2 & 7) << 3)]);
    }
    int b = b0 + bb;
    int ocol = (h_base + h2) * 64 + d;
    ctx[(size_t)b * 1024 + (ocol ^ ((b & 7) << 3))] = f2bf(c);
  }
}

extern "C" void kernel_launch(void* const* d_in, const int* in_sizes, int n_in,
                              void* d_out, int out_size, void* d_ws, size_t ws_size,
                              hipStream_t stream) {
  (void)in_sizes; (void)n_in; (void)out_size; (void)ws_size;
  const float* x     = (const float*)d_in[0];
  const float* ph    = (const float*)d_in[1];
  const float* pcell = (const float*)d_in[2];
  const float* pcs   = (const float*)d_in[3];
  const float* W_ih  = (const float*)d_in[4];
  const float* b_ih  = (const float*)d_in[5];
  const float* W_hh  = (const float*)d_in[6];
  const float* W_q   = (const float*)d_in[7];
  const float* b_q   = (const float*)d_in[8];
  const float* W_ac  = (const float*)d_in[9];
  const float* b_ac  = (const float*)d_in[10];
  const float* Wq_a  = (const float*)d_in[11];
  const float* bq_a  = (const float*)d_in[12];
  const float* Wk_a  = (const float*)d_in[13];
  const float* bk_a  = (const float*)d_in[14];
  const float* Wv_a  = (const float*)d_in[15];
  const float* bv_a  = (const float*)d_in[16];
  const float* Wo_a  = (const float*)d_in[17];
  const float* bo_a  = (const float*)d_in[18];

  char* wp = (char*)d_ws;
  auto alloc = [&](size_t bytes) {
    char* r = wp; wp += (bytes + 255) & ~(size_t)255; return r;
  };
  unsigned short* A_pc  = (unsigned short*)alloc((size_t)16384 * 1024 * 2);
  unsigned short* W6    = (unsigned short*)alloc((size_t)4096 * 2560 * 2);
  unsigned short* Wq    = (unsigned short*)alloc((size_t)1024 * 1536 * 2);
  unsigned short* Wqa   = (unsigned short*)alloc((size_t)1024 * 1024 * 2);
  unsigned short* Woa   = (unsigned short*)alloc((size_t)1024 * 1024 * 2);
  unsigned short* Wkv   = (unsigned short*)alloc((size_t)2048 * 1024 * 2);
  unsigned short* A6    = (unsigned short*)alloc((size_t)512 * 2560 * 2);
  unsigned short* q_bf  = (unsigned short*)alloc((size_t)512 * 1024 * 2);
  float*          Qf    = (float*)alloc((size_t)512 * 1024 * 4);
  unsigned short* ctxbf = (unsigned short*)alloc((size_t)512 * 1024 * 2);
  float*          peb   = (float*)alloc((size_t)32 * 2048 * 4);
  float*          bias6 = (float*)alloc((size_t)4096 * 4);
  float*          s1    = (float*)alloc((size_t)1024 * 4);
  float*          t1    = (float*)alloc((size_t)1024 * 4);
  float*          s2    = (float*)alloc((size_t)1024 * 4);
  float*          t2    = (float*)alloc((size_t)1024 * 4);

  {
    CP cp = {};
    cp.pcs = pcs; cp.W_ih = W_ih; cp.W_hh = W_hh; cp.W_ac = W_ac; cp.W_q = W_q;
    cp.Wq_a = Wq_a; cp.Wo_a = Wo_a; cp.Wk_a = Wk_a; cp.Wv_a = Wv_a;
    cp.x = x; cp.ph = ph;
    cp.b_ih = b_ih; cp.b_ac = b_ac; cp.bk = bk_a; cp.bv = bv_a;
    cp.g1 = (const float*)d_in[19]; cp.be1 = (const float*)d_in[20];
    cp.m1 = (const float*)d_in[21]; cp.v1 = (const float*)d_in[22];
    cp.g2 = (const float*)d_in[23]; cp.be2 = (const float*)d_in[24];
    cp.m2 = (const float*)d_in[25]; cp.v2 = (const float*)d_in[26];
    cp.A_pc = A_pc; cp.W6 = W6; cp.Wq = Wq; cp.Wqa = Wqa; cp.Woa = Woa;
    cp.Wkv = Wkv; cp.A6 = A6;
    cp.peb = peb; cp.bias6 = bias6; cp.s1 = s1; cp.t1 = t1; cp.s2 = s2; cp.t2 = t2;
    cast_all<<<16784, 256, 0, stream>>>(cp);
  }

  // G1: q = elu([x|ph] @ W_q^T + b_q) -> q_bf (swizzled)
  {
    GP2 p = {};
    p.A = A6; p.lda = 2560; p.B = Wq; p.ldb = 1536;
    p.bias = b_q; p.ob = q_bf; p.N = 1024; p.K = 1536;
    sgemm<32, 64, 1, 1><<<dim3(16, 16), 256, 0, stream>>>(p);
  }
  // G2: Q = q @ Wq_a^T + bq_a -> Qf (f32 linear)
  {
    GP2 p = {};
    p.A = q_bf; p.lda = 1024; p.B = Wqa; p.ldb = 1024;
    p.bias = bq_a; p.of = Qf; p.N = 1024; p.K = 1024;
    sgemm<32, 64, 0, 0><<<dim3(16, 16), 256, 0, stream>>>(p);
  }
  // fused K/V GEMM + attention -> ctxbf (swizzled). 1024 blocks (2 heads each)
  gkv_attn<<<1024, 256, 0, stream>>>(A_pc, Wkv, peb, Qf, ctxbf);
  // G5: attn = bn(elu(ctx @ Wo_a^T + bo_a)) -> A6 cols 1536.. (bf16 swizzled)
  {
    GP2 p = {};
    p.A = ctxbf; p.lda = 1024; p.B = Woa; p.ldb = 1024;
    p.bias = bo_a; p.bnS = s1; p.bnT = t1; p.ob = A6; p.N = 1024; p.K = 1024;
    sgemm<32, 64, 3, 1><<<dim3(16, 16), 256, 0, stream>>>(p);
  }
  // G6 + fused final: hidden -> d_out (f32). Gate-interleaved W6/bias6.
  {
    GP2 p = {};
    p.A = A6; p.lda = 2560; p.B = W6; p.ldb = 2560;
    p.bias = bias6; p.bnS = s2; p.bnT = t2; p.pcell = pcell;
    p.of = (float*)d_out; p.N = 4096; p.K = 2560;
    sgemm<64, 64, 4, 0><<<dim3(64, 8), 256, 0, stream>>>(p);
  }
}